// Round 2
// baseline (416.960 us; speedup 1.0000x reference)
//
#include <hip/hip_runtime.h>

// Problem constants
constexpr int kB  = 2;
constexpr int kL  = 8192;   // d*h*w = 8*32*32
constexpr int kC  = 128;    // D_MODEL
constexpr int kE  = 256;    // D_INNER
constexpr int kN  = 16;     // D_STATE
constexpr int kCL = 64;     // scan chunk length
constexpr int kNC = kL / kCL; // 128 chunks per batch

__device__ __forceinline__ float silu(float v) {
  return v / (1.f + __expf(-v));
}

// ---------------------------------------------------------------------------
// Kernel 1: per-token LN stats only (mu, rsqrt). x is [b][c][L].
// ---------------------------------------------------------------------------
__global__ __launch_bounds__(256) void k_stats(const float* __restrict__ x,
                                               float* __restrict__ muA,
                                               float* __restrict__ rsA) {
  __shared__ float tile[64][129];
  const int b  = blockIdx.y;
  const int l0 = blockIdx.x * 64;
  const int tid = threadIdx.x;
  const int cc = tid >> 6, lt = tid & 63;
  const float* xb = x + (size_t)b * kC * kL;
  for (int c0 = 0; c0 < kC; c0 += 4) {
    tile[lt][c0 + cc] = xb[(size_t)(c0 + cc) * kL + l0 + lt];
  }
  __syncthreads();
  const int l = tid >> 2, q = tid & 3;
  float s = 0.f, s2 = 0.f;
  #pragma unroll
  for (int i = 0; i < 32; ++i) {
    float v = tile[l][q + 4 * i];
    s += v; s2 += v * v;
  }
  s  += __shfl_xor(s, 1);  s2 += __shfl_xor(s2, 1);
  s  += __shfl_xor(s, 2);  s2 += __shfl_xor(s2, 2);
  if (q == 0) {
    const float mu  = s * (1.f / 128.f);
    const float var = s2 * (1.f / 128.f) - mu * mu;
    muA[(size_t)b * kL + l0 + l] = mu;
    rsA[(size_t)b * kL + l0 + l] = rsqrtf(var + 1e-5f);
  }
}

// ---------------------------------------------------------------------------
// Kernel 2: xz = LN(x) @ W_in^T, LN fused into A-staging.
// Output transposed: xiT/zT [b][e][L]. Tile 64 l x 128 e, K=128 in 2 chunks.
// ---------------------------------------------------------------------------
__global__ __launch_bounds__(256) void k_gemm1(const float* __restrict__ x,
                                               const float* __restrict__ muA,
                                               const float* __restrict__ rsA,
                                               const float* __restrict__ ln_w,
                                               const float* __restrict__ ln_b,
                                               const float* __restrict__ W_in,
                                               float* __restrict__ xiT,
                                               float* __restrict__ zT) {
  __shared__ float smem[12800];           // As[64*68] ++ Bs[64*132]
  float* As = smem;                       // [c][l], pad 68
  float* Bs = smem + 4352;                // [c][e], pad 132
  const int b  = blockIdx.z;
  const int l0 = blockIdx.x * 64;
  const int et = blockIdx.y;              // 0..3 (128-wide e slices)
  const int tid = threadIdx.x;
  const int eg = tid >> 4, lg = tid & 15;
  float acc[8][4];
  #pragma unroll
  for (int j = 0; j < 8; ++j)
    #pragma unroll
    for (int i = 0; i < 4; ++i) acc[j][i] = 0.f;

  const float* Wb = W_in + (size_t)et * 128 * kC;
  for (int c0 = 0; c0 < kC; c0 += 64) {
    // stage As = LN(x)^T chunk [64 c][64 l]
    #pragma unroll
    for (int it = 0; it < 4; ++it) {
      const int idx = tid + it * 256;          // 0..1023
      const int cc = idx >> 4, l4 = idx & 15;
      const float4 v   = *(const float4*)&x[((size_t)b * kC + c0 + cc) * kL + l0 + 4 * l4];
      const float4 muv = *(const float4*)&muA[(size_t)b * kL + l0 + 4 * l4];
      const float4 rsv = *(const float4*)&rsA[(size_t)b * kL + l0 + 4 * l4];
      const float wv = ln_w[c0 + cc], bv = ln_b[c0 + cc];
      float4 o;
      o.x = (v.x - muv.x) * rsv.x * wv + bv;
      o.y = (v.y - muv.y) * rsv.y * wv + bv;
      o.z = (v.z - muv.z) * rsv.z * wv + bv;
      o.w = (v.w - muv.w) * rsv.w * wv + bv;
      *(float4*)&As[cc * 68 + 4 * l4] = o;
    }
    // stage Bs = W^T chunk [64 c][128 e]
    #pragma unroll
    for (int it = 0; it < 8; ++it) {
      const int idx = tid + it * 256;          // 0..2047
      const int e = idx >> 4, c4 = idx & 15;
      const float4 v = *(const float4*)&Wb[(size_t)e * kC + c0 + 4 * c4];
      Bs[(4 * c4 + 0) * 132 + e] = v.x;
      Bs[(4 * c4 + 1) * 132 + e] = v.y;
      Bs[(4 * c4 + 2) * 132 + e] = v.z;
      Bs[(4 * c4 + 3) * 132 + e] = v.w;
    }
    __syncthreads();
    #pragma unroll 2
    for (int k = 0; k < 64; ++k) {
      const float4 av = *(const float4*)&As[k * 68 + 4 * lg];
      const float4 w0 = *(const float4*)&Bs[k * 132 + 8 * eg];
      const float4 w1 = *(const float4*)&Bs[k * 132 + 8 * eg + 4];
      const float a[4] = {av.x, av.y, av.z, av.w};
      const float w[8] = {w0.x, w0.y, w0.z, w0.w, w1.x, w1.y, w1.z, w1.w};
      #pragma unroll
      for (int j = 0; j < 8; ++j)
        #pragma unroll
        for (int i = 0; i < 4; ++i) acc[j][i] = fmaf(w[j], a[i], acc[j][i]);
    }
    __syncthreads();
  }
  // bounce acc through LDS as [e][l], then write rows of xiT/zT
  float* T = smem;                         // [128][68], 8704 <= 12800
  #pragma unroll
  for (int j = 0; j < 8; ++j) {
    float4 v; v.x = acc[j][0]; v.y = acc[j][1]; v.z = acc[j][2]; v.w = acc[j][3];
    *(float4*)&T[(8 * eg + j) * 68 + 4 * lg] = v;
  }
  __syncthreads();
  float* dst = (et < 2) ? xiT : zT;
  const int ebase = (et & 1) * 128;
  #pragma unroll
  for (int it = 0; it < 8; ++it) {
    const int idx = tid + it * 256;          // 0..2047
    const int e = idx >> 4, l4 = idx & 15;
    const float4 v = *(const float4*)&T[e * 68 + 4 * l4];
    *(float4*)&dst[((size_t)b * kE + ebase + e) * kL + l0 + 4 * l4] = v;
  }
}

// ---------------------------------------------------------------------------
// Kernel 3: depthwise causal conv + silu.  xiT [b][e][L] -> xcT [b][e][L]
// thread = 16-token chunk of one (b,e) row
// ---------------------------------------------------------------------------
__global__ __launch_bounds__(256) void k_conv(const float* __restrict__ xiT,
                                              const float* __restrict__ conv_w,
                                              const float* __restrict__ conv_b,
                                              float* __restrict__ xcT) {
  const int t = blockIdx.x * 256 + threadIdx.x;   // B*E*(L/16) = 262144
  const int ci  = t & 511;                        // chunk in row
  const int row = t >> 9;                         // b*256+e
  const int e   = row & 255;
  const float4 cw = ((const float4*)conv_w)[e];
  const float cb = conv_b[e];
  const size_t base = (size_t)row * kL + ci * 16;
  const float4* src = (const float4*)(xiT + base);
  float xb[20];
  if (ci) {
    const float4 p = src[-1];
    xb[0] = p.x; xb[1] = p.y; xb[2] = p.z; xb[3] = p.w;
  } else {
    xb[0] = xb[1] = xb[2] = xb[3] = 0.f;
  }
  #pragma unroll
  for (int m = 0; m < 4; ++m) {
    const float4 v = src[m];
    xb[4 + 4 * m] = v.x; xb[5 + 4 * m] = v.y; xb[6 + 4 * m] = v.z; xb[7 + 4 * m] = v.w;
  }
  float4* dst = (float4*)(xcT + base);
  #pragma unroll
  for (int m = 0; m < 4; ++m) {
    float o[4];
    #pragma unroll
    for (int i = 0; i < 4; ++i) {
      const int p = 4 * m + i;
      float s = cb + cw.x * xb[p + 1] + cw.y * xb[p + 2] + cw.z * xb[p + 3] + cw.w * xb[p + 4];
      o[i] = silu(s);
    }
    float4 ov; ov.x = o[0]; ov.y = o[1]; ov.z = o[2]; ov.w = o[3];
    dst[m] = ov;
  }
}

// ---------------------------------------------------------------------------
// Kernel 4: dbl = xc @ W_x^T (N=40), then Bm/Cm split and
//           dt = softplus(dbl[:, :8] @ W_dt^T + b_dt) -> dtT [b][e][L]
// Tile 64 tokens; wave-uniform W reads (broadcast).
// ---------------------------------------------------------------------------
__global__ __launch_bounds__(256) void k_dbl(const float* __restrict__ xcT,
                                             const float* __restrict__ W_x,
                                             const float* __restrict__ W_dt,
                                             const float* __restrict__ b_dt,
                                             float* __restrict__ dtT,
                                             float* __restrict__ Bm,
                                             float* __restrict__ Cm) {
  __shared__ float Wxs[40 * 256];
  __shared__ float As[64 * 68];     // xcT chunk [c][l]
  __shared__ float dblt[64 * 44];   // [l][o], pad 44
  __shared__ float Wdts[256 * 8];
  __shared__ float bdts[256];
  const int b  = blockIdx.y;
  const int l0 = blockIdx.x * 64;
  const int tid = threadIdx.x;
  for (int idx = tid; idx < 40 * 256 / 4; idx += 256)
    ((float4*)Wxs)[idx] = ((const float4*)W_x)[idx];
  for (int idx = tid; idx < 256 * 8 / 4; idx += 256)
    ((float4*)Wdts)[idx] = ((const float4*)W_dt)[idx];
  bdts[tid] = b_dt[tid];

  const int og = tid >> 6;          // wave id: 10 outputs each
  const int l  = tid & 63;
  float acc[10];
  #pragma unroll
  for (int j = 0; j < 10; ++j) acc[j] = 0.f;

  for (int c0 = 0; c0 < kE; c0 += 64) {
    #pragma unroll
    for (int it = 0; it < 4; ++it) {
      const int idx = tid + it * 256;
      const int cc = idx >> 4, l4 = idx & 15;
      const float4 v = *(const float4*)&xcT[((size_t)b * kE + c0 + cc) * kL + l0 + 4 * l4];
      *(float4*)&As[cc * 68 + 4 * l4] = v;
    }
    __syncthreads();
    for (int k = 0; k < 64; k += 4) {
      const float a0 = As[(k + 0) * 68 + l];
      const float a1 = As[(k + 1) * 68 + l];
      const float a2 = As[(k + 2) * 68 + l];
      const float a3 = As[(k + 3) * 68 + l];
      #pragma unroll
      for (int j = 0; j < 10; ++j) {
        const float4 wv = *(const float4*)&Wxs[(10 * og + j) * 256 + c0 + k];
        acc[j] = fmaf(a0, wv.x, acc[j]);
        acc[j] = fmaf(a1, wv.y, acc[j]);
        acc[j] = fmaf(a2, wv.z, acc[j]);
        acc[j] = fmaf(a3, wv.w, acc[j]);
      }
    }
    __syncthreads();
  }
  #pragma unroll
  for (int j = 0; j < 10; ++j) dblt[l * 44 + 10 * og + j] = acc[j];
  __syncthreads();
  // Bm / Cm (layout [b][l][16])
  for (int idx = tid; idx < 1024; idx += 256) {
    const int li = idx >> 4, n = idx & 15;
    const size_t o = ((size_t)b * kL + l0 + li) * kN + n;
    Bm[o] = dblt[li * 44 + 8 + n];
    Cm[o] = dblt[li * 44 + 24 + n];
  }
  // dt GEMM (R=8) + softplus, write dtT rows
  const float4 d0v = *(const float4*)&dblt[l * 44];
  const float4 d1v = *(const float4*)&dblt[l * 44 + 4];
  const int dbase = og * 64;
  for (int d = dbase; d < dbase + 64; ++d) {
    const float4 w0 = *(const float4*)&Wdts[d * 8];
    const float4 w1 = *(const float4*)&Wdts[d * 8 + 4];
    float s = bdts[d];
    s = fmaf(d0v.x, w0.x, s); s = fmaf(d0v.y, w0.y, s);
    s = fmaf(d0v.z, w0.z, s); s = fmaf(d0v.w, w0.w, s);
    s = fmaf(d1v.x, w1.x, s); s = fmaf(d1v.y, w1.y, s);
    s = fmaf(d1v.z, w1.z, s); s = fmaf(d1v.w, w1.w, s);
    s = fmaxf(s, 0.f) + log1pf(__expf(-fabsf(s)));
    dtT[((size_t)b * kE + d) * kL + l0 + l] = s;
  }
}

// ---------------------------------------------------------------------------
// Kernel 5: scan phase A — per-chunk local scan (zero init) + chunk product
// ---------------------------------------------------------------------------
__global__ __launch_bounds__(256) void k_scanA(const float* __restrict__ dtT,
                                               const float* __restrict__ xcT,
                                               const float* __restrict__ Bm,
                                               const float* __restrict__ A_log,
                                               float* __restrict__ hloc,
                                               float* __restrict__ aprod) {
  __shared__ float dtt[64 * 68];
  __shared__ float xct[64 * 68];
  __shared__ float Bmt[64 * 16];
  const int b  = blockIdx.z;
  const int ch = blockIdx.x;
  const int d0 = blockIdx.y * 64;
  const int l0 = ch * kCL;
  const int tid = threadIdx.x;
  #pragma unroll
  for (int it = 0; it < 4; ++it) {
    const int idx = tid + it * 256;
    const int dd = idx >> 4, l4 = idx & 15;
    *(float4*)&dtt[dd * 68 + 4 * l4] = *(const float4*)&dtT[((size_t)b * kE + d0 + dd) * kL + l0 + 4 * l4];
    *(float4*)&xct[dd * 68 + 4 * l4] = *(const float4*)&xcT[((size_t)b * kE + d0 + dd) * kL + l0 + 4 * l4];
  }
  {
    const int li = tid >> 2, n4 = tid & 3;
    *(float4*)&Bmt[li * 16 + 4 * n4] = *(const float4*)&Bm[((size_t)b * kL + l0 + li) * kN + 4 * n4];
  }
  __syncthreads();
  const int ds = tid >> 2, ng = tid & 3;
  const int d = d0 + ds;
  float Av[4];
  #pragma unroll
  for (int j = 0; j < 4; ++j) Av[j] = -__expf(A_log[d * kN + 4 * ng + j]);
  float h[4] = {0.f, 0.f, 0.f, 0.f};
  float sdt = 0.f;
  for (int l = 0; l < kCL; ++l) {
    const float dtv = dtt[ds * 68 + l];
    const float dx  = dtv * xct[ds * 68 + l];
    sdt += dtv;
    #pragma unroll
    for (int j = 0; j < 4; ++j) {
      const float dA = __expf(Av[j] * dtv);
      h[j] = fmaf(dA, h[j], Bmt[l * 16 + 4 * ng + j] * dx);
    }
  }
  const size_t base = (((size_t)b * kNC + ch) * kE + d) * kN + 4 * ng;
  float4 hv; hv.x = h[0]; hv.y = h[1]; hv.z = h[2]; hv.w = h[3];
  *(float4*)&hloc[base] = hv;
  float4 ap;
  ap.x = __expf(Av[0] * sdt); ap.y = __expf(Av[1] * sdt);
  ap.z = __expf(Av[2] * sdt); ap.w = __expf(Av[3] * sdt);
  *(float4*)&aprod[base] = ap;
}

// ---------------------------------------------------------------------------
// Kernel 6: sequential prefix over chunks (tiny)
// ---------------------------------------------------------------------------
__global__ __launch_bounds__(256) void k_prefix(const float* __restrict__ hloc,
                                                const float* __restrict__ aprod,
                                                float* __restrict__ hinit) {
  const int t = blockIdx.x * 256 + threadIdx.x;  // 8192 = B*E*N
  const int b = t >> 12, dn = t & 4095;
  float h = 0.f;
  #pragma unroll 4
  for (int c = 0; c < kNC; ++c) {
    const size_t idx = ((size_t)b * kNC + c) * 4096 + dn;
    hinit[idx] = h;
    h = fmaf(aprod[idx], h, hloc[idx]);
  }
}

// ---------------------------------------------------------------------------
// Kernel 7: scan phase C — real scan with init, y = sum_n h*C,
//           fused gating: yT = (y + xc*D) * silu(z)
// ---------------------------------------------------------------------------
__global__ __launch_bounds__(256) void k_scanC(const float* __restrict__ dtT,
                                               const float* __restrict__ xcT,
                                               const float* __restrict__ Bm,
                                               const float* __restrict__ Cm,
                                               const float* __restrict__ zT,
                                               const float* __restrict__ A_log,
                                               const float* __restrict__ Dp,
                                               const float* __restrict__ hinit,
                                               float* __restrict__ yT) {
  __shared__ float dtt[64 * 68];
  __shared__ float xct[64 * 68];
  __shared__ float yt[64 * 68];
  __shared__ float Bmt[64 * 16];
  __shared__ float Cmt[64 * 16];
  const int b  = blockIdx.z;
  const int ch = blockIdx.x;
  const int d0 = blockIdx.y * 64;
  const int l0 = ch * kCL;
  const int tid = threadIdx.x;
  #pragma unroll
  for (int it = 0; it < 4; ++it) {
    const int idx = tid + it * 256;
    const int dd = idx >> 4, l4 = idx & 15;
    *(float4*)&dtt[dd * 68 + 4 * l4] = *(const float4*)&dtT[((size_t)b * kE + d0 + dd) * kL + l0 + 4 * l4];
    *(float4*)&xct[dd * 68 + 4 * l4] = *(const float4*)&xcT[((size_t)b * kE + d0 + dd) * kL + l0 + 4 * l4];
  }
  {
    const int li = tid >> 2, n4 = tid & 3;
    *(float4*)&Bmt[li * 16 + 4 * n4] = *(const float4*)&Bm[((size_t)b * kL + l0 + li) * kN + 4 * n4];
    *(float4*)&Cmt[li * 16 + 4 * n4] = *(const float4*)&Cm[((size_t)b * kL + l0 + li) * kN + 4 * n4];
  }
  __syncthreads();
  const int ds = tid >> 2, ng = tid & 3;
  const int d = d0 + ds;
  float Av[4];
  #pragma unroll
  for (int j = 0; j < 4; ++j) Av[j] = -__expf(A_log[d * kN + 4 * ng + j]);
  const float4 hv = *(const float4*)&hinit[(((size_t)b * kNC + ch) * kE + d) * kN + 4 * ng];
  float h[4] = {hv.x, hv.y, hv.z, hv.w};
  for (int l = 0; l < kCL; ++l) {
    const float dtv = dtt[ds * 68 + l];
    const float dx  = dtv * xct[ds * 68 + l];
    float yp = 0.f;
    #pragma unroll
    for (int j = 0; j < 4; ++j) {
      const float dA = __expf(Av[j] * dtv);
      h[j] = fmaf(dA, h[j], Bmt[l * 16 + 4 * ng + j] * dx);
      yp = fmaf(h[j], Cmt[l * 16 + 4 * ng + j], yp);
    }
    yp += __shfl_xor(yp, 1);
    yp += __shfl_xor(yp, 2);
    if (ng == 0) yt[ds * 68 + l] = yp;
  }
  __syncthreads();
  // gating + write yT rows
  #pragma unroll
  for (int it = 0; it < 4; ++it) {
    const int idx = tid + it * 256;
    const int dd = idx >> 4, l4 = idx & 15;
    const float4 yv = *(const float4*)&yt[dd * 68 + 4 * l4];
    const float4 xv = *(const float4*)&xct[dd * 68 + 4 * l4];
    const float4 zv = *(const float4*)&zT[((size_t)b * kE + d0 + dd) * kL + l0 + 4 * l4];
    const float Dv = Dp[d0 + dd];
    float4 o;
    o.x = fmaf(xv.x, Dv, yv.x) * silu(zv.x);
    o.y = fmaf(xv.y, Dv, yv.y) * silu(zv.y);
    o.z = fmaf(xv.z, Dv, yv.z) * silu(zv.z);
    o.w = fmaf(xv.w, Dv, yv.w) * silu(zv.w);
    *(float4*)&yT[((size_t)b * kE + d0 + dd) * kL + l0 + 4 * l4] = o;
  }
}

// ---------------------------------------------------------------------------
// Kernel 8: out[b][c][L] = W_out @ yT  (64c x 64l tiles, K=256 in 4 chunks)
// ---------------------------------------------------------------------------
__global__ __launch_bounds__(256) void k_gemm3(const float* __restrict__ yT,
                                               const float* __restrict__ W_out,
                                               float* __restrict__ out) {
  __shared__ float As[64 * 68];  // [k][l]
  __shared__ float Bs[64 * 68];  // [k][c]
  const int b   = blockIdx.z;
  const int l0  = blockIdx.x * 64;
  const int c00 = blockIdx.y * 64;
  const int tid = threadIdx.x;
  const int cg = tid >> 4, lg = tid & 15;
  float acc[4][4];
  #pragma unroll
  for (int j = 0; j < 4; ++j)
    #pragma unroll
    for (int i = 0; i < 4; ++i) acc[j][i] = 0.f;
  for (int k0 = 0; k0 < kE; k0 += 64) {
    #pragma unroll
    for (int it = 0; it < 4; ++it) {
      const int idx = tid + it * 256;
      const int kk = idx >> 4, l4 = idx & 15;
      *(float4*)&As[kk * 68 + 4 * l4] = *(const float4*)&yT[((size_t)b * kE + k0 + kk) * kL + l0 + 4 * l4];
    }
    #pragma unroll
    for (int it = 0; it < 4; ++it) {
      const int idx = tid + it * 256;
      const int c = idx >> 4, k4 = idx & 15;
      const float4 v = *(const float4*)&W_out[(size_t)(c00 + c) * kE + k0 + 4 * k4];
      Bs[(4 * k4 + 0) * 68 + c] = v.x;
      Bs[(4 * k4 + 1) * 68 + c] = v.y;
      Bs[(4 * k4 + 2) * 68 + c] = v.z;
      Bs[(4 * k4 + 3) * 68 + c] = v.w;
    }
    __syncthreads();
    #pragma unroll 2
    for (int k = 0; k < 64; ++k) {
      const float4 av = *(const float4*)&As[k * 68 + 4 * lg];
      const float4 wv = *(const float4*)&Bs[k * 68 + 4 * cg];
      const float a[4] = {av.x, av.y, av.z, av.w};
      const float w[4] = {wv.x, wv.y, wv.z, wv.w};
      #pragma unroll
      for (int j = 0; j < 4; ++j)
        #pragma unroll
        for (int i = 0; i < 4; ++i) acc[j][i] = fmaf(w[j], a[i], acc[j][i]);
    }
    __syncthreads();
  }
  #pragma unroll
  for (int j = 0; j < 4; ++j) {
    float4 v; v.x = acc[j][0]; v.y = acc[j][1]; v.z = acc[j][2]; v.w = acc[j][3];
    *(float4*)&out[((size_t)b * kC + c00 + 4 * cg + j) * kL + l0 + 4 * lg] = v;
  }
}

// ---------------------------------------------------------------------------
extern "C" void kernel_launch(void* const* d_in, const int* in_sizes, int n_in,
                              void* d_out, int out_size, void* d_ws, size_t ws_size,
                              hipStream_t stream) {
  (void)in_sizes; (void)n_in; (void)out_size; (void)ws_size;
  const float* x      = (const float*)d_in[0];
  const float* ln_w   = (const float*)d_in[1];
  const float* ln_b   = (const float*)d_in[2];
  const float* W_in   = (const float*)d_in[3];
  const float* conv_w = (const float*)d_in[4];
  const float* conv_b = (const float*)d_in[5];
  const float* W_x    = (const float*)d_in[6];
  const float* W_dt   = (const float*)d_in[7];
  const float* b_dt   = (const float*)d_in[8];
  const float* A_log  = (const float*)d_in[9];
  const float* Dp     = (const float*)d_in[10];
  const float* W_out  = (const float*)d_in[11];
  float* out = (float*)d_out;
  float* ws  = (float*)d_ws;

  // workspace layout (floats), total 20,447,232 = ~81.8 MB
  float* xiT   = ws;                   // 4,194,304  [b][e][L]  (reused as yT)
  float* zT    = ws + 4194304;         // 4,194,304
  float* xcT   = ws + 8388608;         // 4,194,304
  float* dtT   = ws + 12582912;        // 4,194,304
  float* Bm    = ws + 16777216;        //   262,144  [b][l][16]
  float* Cm    = ws + 17039360;        //   262,144
  float* hloc  = ws + 17301504;        // 1,048,576
  float* aprod = ws + 18350080;        // 1,048,576
  float* hinit = ws + 19398656;        // 1,048,576
  float* muA   = hinit;                // 16,384 (dead before prefix writes hinit)
  float* rsA   = hinit + 16384;        // 16,384
  float* yT    = xiT;                  // xiT dead after conv

  k_stats <<<dim3(kL / 64, kB),       256, 0, stream>>>(x, muA, rsA);
  k_gemm1 <<<dim3(kL / 64, 4, kB),    256, 0, stream>>>(x, muA, rsA, ln_w, ln_b, W_in, xiT, zT);
  k_conv  <<<dim3(kB * kE * (kL / 16) / 256), 256, 0, stream>>>(xiT, conv_w, conv_b, xcT);
  k_dbl   <<<dim3(kL / 64, kB),       256, 0, stream>>>(xcT, W_x, W_dt, b_dt, dtT, Bm, Cm);
  k_scanA <<<dim3(kNC, kE / 64, kB),  256, 0, stream>>>(dtT, xcT, Bm, A_log, hloc, aprod);
  k_prefix<<<dim3(kB * kE * kN / 256), 256, 0, stream>>>(hloc, aprod, hinit);
  k_scanC <<<dim3(kNC, kE / 64, kB),  256, 0, stream>>>(dtT, xcT, Bm, Cm, zT, A_log, Dp, hinit, yT);
  k_gemm3 <<<dim3(kL / 64, 2, kB),    256, 0, stream>>>(yT, W_out, out);
}

// Round 3
// 214.918 us; speedup vs baseline: 1.9401x; 1.9401x over previous
//
#include <hip/hip_runtime.h>

// Problem constants
constexpr int kB  = 2;
constexpr int kL  = 8192;   // d*h*w = 8*32*32
constexpr int kC  = 128;    // D_MODEL
constexpr int kE  = 256;    // D_INNER
constexpr int kN  = 16;     // D_STATE
constexpr int kCL = 64;     // scan chunk length
constexpr int kNC = kL / kCL; // 128 chunks per batch

__device__ __forceinline__ float silu(float v) {
  return v / (1.f + __expf(-v));
}
__device__ __forceinline__ float softplus(float s) {
  return fmaxf(s, 0.f) + log1pf(__expf(-fabsf(s)));
}

// ---------------------------------------------------------------------------
// Kernel 0: weight prep.
//  blocks 0..15 : W_inT[c][e]   = W_in[e][c]            (128 x 512)
//  block  16    : WcatT[k][256+j] = W_x[8+j][k]         (B/C rows)
//  blocks 17..32: WcatT[k][e]   = sum_r W_dt[e][r]*W_x[r][k]   (dt fold)
//  blocks 33..40: W_outT[k][c]  = W_out[c][k]           (256 x 128)
// ---------------------------------------------------------------------------
__global__ __launch_bounds__(256) void k_prep(const float* __restrict__ W_in,
                                              const float* __restrict__ W_x,
                                              const float* __restrict__ W_dt,
                                              const float* __restrict__ W_out,
                                              float* __restrict__ W_inT,
                                              float* __restrict__ WcatT,
                                              float* __restrict__ W_outT) {
  const int blk = blockIdx.x;
  const int tid = threadIdx.x;
  if (blk < 16) {
    #pragma unroll
    for (int it = 0; it < 16; ++it) {
      const int flat = blk * 4096 + it * 256 + tid;   // 65536 elems
      const int e = flat >> 7, c = flat & 127;
      W_inT[c * 512 + e] = W_in[flat];
    }
  } else if (blk == 16) {
    #pragma unroll
    for (int it = 0; it < 32; ++it) {
      const int flat = it * 256 + tid;                // 8192 elems
      const int j = flat >> 8, k = flat & 255;
      WcatT[k * 288 + 256 + j] = W_x[(8 + j) * 256 + k];
    }
  } else if (blk < 33) {
    __shared__ float wx[8 * 256];
    #pragma unroll
    for (int it = 0; it < 8; ++it) wx[it * 256 + tid] = W_x[it * 256 + tid];
    __syncthreads();
    const int kb = (blk - 17) * 16;
    const int e = tid;
    float wdt[8];
    #pragma unroll
    for (int r = 0; r < 8; ++r) wdt[r] = W_dt[e * 8 + r];
    #pragma unroll
    for (int kk = 0; kk < 16; ++kk) {
      const int k = kb + kk;
      float s = 0.f;
      #pragma unroll
      for (int r = 0; r < 8; ++r) s = fmaf(wdt[r], wx[r * 256 + k], s);
      WcatT[k * 288 + e] = s;
    }
  } else {
    #pragma unroll
    for (int it = 0; it < 16; ++it) {
      const int flat = (blk - 33) * 4096 + it * 256 + tid;  // 32768 elems
      const int c = flat >> 8, k = flat & 255;
      W_outT[k * 128 + c] = W_out[flat];
    }
  }
}

// ---------------------------------------------------------------------------
// Kernel 1: per-token LN stats only (mu, rsqrt). x is [b][c][L].
// ---------------------------------------------------------------------------
__global__ __launch_bounds__(256) void k_stats(const float* __restrict__ x,
                                               float* __restrict__ muA,
                                               float* __restrict__ rsA) {
  __shared__ float tile[64][129];
  const int b  = blockIdx.y;
  const int l0 = blockIdx.x * 64;
  const int tid = threadIdx.x;
  const int cc = tid >> 6, lt = tid & 63;
  const float* xb = x + (size_t)b * kC * kL;
  for (int c0 = 0; c0 < kC; c0 += 4) {
    tile[lt][c0 + cc] = xb[(size_t)(c0 + cc) * kL + l0 + lt];
  }
  __syncthreads();
  const int l = tid >> 2, q = tid & 3;
  float s = 0.f, s2 = 0.f;
  #pragma unroll
  for (int i = 0; i < 32; ++i) {
    float v = tile[l][q + 4 * i];
    s += v; s2 += v * v;
  }
  s  += __shfl_xor(s, 1);  s2 += __shfl_xor(s2, 1);
  s  += __shfl_xor(s, 2);  s2 += __shfl_xor(s2, 2);
  if (q == 0) {
    const float mu  = s * (1.f / 128.f);
    const float var = s2 * (1.f / 128.f) - mu * mu;
    muA[(size_t)b * kL + l0 + l] = mu;
    rsA[(size_t)b * kL + l0 + l] = rsqrtf(var + 1e-5f);
  }
}

// ---------------------------------------------------------------------------
// Unified scalar-weight GEMM: out[m][l] = sum_k Wt[k][m] * X[k][l]
// Tile: MT channels x 256 l-cols. 4 waves, each owns MT/4 rows (uniform via
// readfirstlane -> s_load weights). Lanes own 4 contiguous l (ds_read_b128).
// VARIANT 0: gemm1 (LN fused into staging; out rows <256 -> xiT, else zT)
// VARIANT 1: dbc   (rows <256 -> softplus(+b_dt) -> dtT; rows 256.. -> bcT)
// VARIANT 2: gemm3 (plain -> out [b][128][L])
// ---------------------------------------------------------------------------
template<int K, int M, int MT, int MP, int VARIANT>
__global__ __launch_bounds__(256) void k_gemm_sw(
    const float* __restrict__ Xsrc,
    const float* __restrict__ Wt,
    const float* __restrict__ muA, const float* __restrict__ rsA,
    const float* __restrict__ lnw, const float* __restrict__ lnb,
    const float* __restrict__ bdt,
    float* __restrict__ out0, float* __restrict__ out1) {
  constexpr int RM = MT / 4;
  __shared__ float As[32 * 256];
  const int b  = blockIdx.z;
  const int ct = blockIdx.y;
  const int l0 = blockIdx.x * 256;
  const int tid = threadIdx.x;
  const int lane = tid & 63;
  const int wv = __builtin_amdgcn_readfirstlane(tid >> 6);
  const int mbase = ct * MT + wv * RM;
  const int sl = 4 * lane;
  const int krow = tid >> 6;

  float4 mu4, rs4;
  if (VARIANT == 0) {
    mu4 = *(const float4*)&muA[(size_t)b * kL + l0 + sl];
    rs4 = *(const float4*)&rsA[(size_t)b * kL + l0 + sl];
  }
  float acc[RM][4];
  #pragma unroll
  for (int m = 0; m < RM; ++m) { acc[m][0] = acc[m][1] = acc[m][2] = acc[m][3] = 0.f; }

  float4 pf[8];
  auto prefetch = [&](int kc) {
    #pragma unroll
    for (int it = 0; it < 8; ++it) {
      const int k = kc + krow + it * 4;
      float4 v = *(const float4*)&Xsrc[((size_t)b * K + k) * kL + l0 + sl];
      if (VARIANT == 0) {
        const float w = lnw[k], bb = lnb[k];
        v.x = (v.x - mu4.x) * rs4.x * w + bb;
        v.y = (v.y - mu4.y) * rs4.y * w + bb;
        v.z = (v.z - mu4.z) * rs4.z * w + bb;
        v.w = (v.w - mu4.w) * rs4.w * w + bb;
      }
      pf[it] = v;
    }
  };

  prefetch(0);
  for (int kc = 0; kc < K; kc += 32) {
    __syncthreads();
    #pragma unroll
    for (int it = 0; it < 8; ++it)
      *(float4*)&As[(krow + it * 4) * 256 + sl] = pf[it];
    __syncthreads();
    if (kc + 32 < K) prefetch(kc + 32);
    #pragma unroll 4
    for (int kk = 0; kk < 32; ++kk) {
      const float4 a = *(const float4*)&As[kk * 256 + sl];
      const float* __restrict__ wr = &Wt[(size_t)(kc + kk) * MP + mbase];
      #pragma unroll
      for (int m = 0; m < RM; ++m) {
        const float wgt = wr[m];
        acc[m][0] = fmaf(wgt, a.x, acc[m][0]);
        acc[m][1] = fmaf(wgt, a.y, acc[m][1]);
        acc[m][2] = fmaf(wgt, a.z, acc[m][2]);
        acc[m][3] = fmaf(wgt, a.w, acc[m][3]);
      }
    }
  }

  if (VARIANT == 0) {
    float* dst = (mbase < 256) ? out0 : out1;
    const int rb = (mbase < 256) ? mbase : mbase - 256;
    #pragma unroll
    for (int m = 0; m < RM; ++m) {
      float4 v = {acc[m][0], acc[m][1], acc[m][2], acc[m][3]};
      *(float4*)&dst[((size_t)b * kE + rb + m) * kL + l0 + sl] = v;
    }
  } else if (VARIANT == 1) {
    if (mbase < 256) {
      #pragma unroll
      for (int m = 0; m < RM; ++m) {
        const float bb = bdt[mbase + m];
        float4 v;
        v.x = softplus(acc[m][0] + bb);
        v.y = softplus(acc[m][1] + bb);
        v.z = softplus(acc[m][2] + bb);
        v.w = softplus(acc[m][3] + bb);
        *(float4*)&out0[((size_t)b * kE + mbase + m) * kL + l0 + sl] = v;
      }
    } else {
      #pragma unroll
      for (int m = 0; m < RM; ++m) {
        float4 v = {acc[m][0], acc[m][1], acc[m][2], acc[m][3]};
        *(float4*)&out1[((size_t)b * 32 + mbase - 256 + m) * kL + l0 + sl] = v;
      }
    }
  } else {
    #pragma unroll
    for (int m = 0; m < RM; ++m) {
      float4 v = {acc[m][0], acc[m][1], acc[m][2], acc[m][3]};
      *(float4*)&out0[((size_t)b * kC + mbase + m) * kL + l0 + sl] = v;
    }
  }
}

// ---------------------------------------------------------------------------
// Kernel: depthwise causal conv + silu.  xiT [b][e][L] -> xcT [b][e][L]
// ---------------------------------------------------------------------------
__global__ __launch_bounds__(256) void k_conv(const float* __restrict__ xiT,
                                              const float* __restrict__ conv_w,
                                              const float* __restrict__ conv_b,
                                              float* __restrict__ xcT) {
  const int t = blockIdx.x * 256 + threadIdx.x;   // B*E*(L/16) = 262144
  const int ci  = t & 511;
  const int row = t >> 9;                         // b*256+e
  const int e   = row & 255;
  const float4 cw = ((const float4*)conv_w)[e];
  const float cb = conv_b[e];
  const size_t base = (size_t)row * kL + ci * 16;
  const float4* src = (const float4*)(xiT + base);
  float xb[20];
  if (ci) {
    const float4 p = src[-1];
    xb[0] = p.x; xb[1] = p.y; xb[2] = p.z; xb[3] = p.w;
  } else {
    xb[0] = xb[1] = xb[2] = xb[3] = 0.f;
  }
  #pragma unroll
  for (int m = 0; m < 4; ++m) {
    const float4 v = src[m];
    xb[4 + 4 * m] = v.x; xb[5 + 4 * m] = v.y; xb[6 + 4 * m] = v.z; xb[7 + 4 * m] = v.w;
  }
  float4* dst = (float4*)(xcT + base);
  #pragma unroll
  for (int m = 0; m < 4; ++m) {
    float o[4];
    #pragma unroll
    for (int i = 0; i < 4; ++i) {
      const int p = 4 * m + i;
      float s = cb + cw.x * xb[p + 1] + cw.y * xb[p + 2] + cw.z * xb[p + 3] + cw.w * xb[p + 4];
      o[i] = silu(s);
    }
    float4 ov; ov.x = o[0]; ov.y = o[1]; ov.z = o[2]; ov.w = o[3];
    dst[m] = ov;
  }
}

// ---------------------------------------------------------------------------
// Kernel: scan phase A — per-chunk local scan (zero init) + chunk product
// B rows are bcT rows 0..15.
// ---------------------------------------------------------------------------
__global__ __launch_bounds__(256) void k_scanA(const float* __restrict__ dtT,
                                               const float* __restrict__ xcT,
                                               const float* __restrict__ bcT,
                                               const float* __restrict__ A_log,
                                               float* __restrict__ hloc,
                                               float* __restrict__ aprod) {
  __shared__ float dtt[64 * 68];
  __shared__ float xct[64 * 68];
  __shared__ float Bmt[16 * 68];
  const int b  = blockIdx.z;
  const int ch = blockIdx.x;
  const int d0 = blockIdx.y * 64;
  const int l0 = ch * kCL;
  const int tid = threadIdx.x;
  #pragma unroll
  for (int it = 0; it < 4; ++it) {
    const int idx = tid + it * 256;
    const int dd = idx >> 4, l4 = idx & 15;
    *(float4*)&dtt[dd * 68 + 4 * l4] = *(const float4*)&dtT[((size_t)b * kE + d0 + dd) * kL + l0 + 4 * l4];
    *(float4*)&xct[dd * 68 + 4 * l4] = *(const float4*)&xcT[((size_t)b * kE + d0 + dd) * kL + l0 + 4 * l4];
  }
  {
    const int n = tid >> 4, l4 = tid & 15;
    *(float4*)&Bmt[n * 68 + 4 * l4] = *(const float4*)&bcT[((size_t)b * 32 + n) * kL + l0 + 4 * l4];
  }
  __syncthreads();
  const int ds = tid >> 2, ng = tid & 3;
  const int d = d0 + ds;
  float Av[4];
  #pragma unroll
  for (int j = 0; j < 4; ++j) Av[j] = -__expf(A_log[d * kN + 4 * ng + j]);
  float h[4] = {0.f, 0.f, 0.f, 0.f};
  float sdt = 0.f;
  for (int l = 0; l < kCL; ++l) {
    const float dtv = dtt[ds * 68 + l];
    const float dx  = dtv * xct[ds * 68 + l];
    sdt += dtv;
    #pragma unroll
    for (int j = 0; j < 4; ++j) {
      const float dA = __expf(Av[j] * dtv);
      h[j] = fmaf(dA, h[j], Bmt[(4 * ng + j) * 68 + l] * dx);
    }
  }
  const size_t base = (((size_t)b * kNC + ch) * kE + d) * kN + 4 * ng;
  float4 hv; hv.x = h[0]; hv.y = h[1]; hv.z = h[2]; hv.w = h[3];
  *(float4*)&hloc[base] = hv;
  float4 ap;
  ap.x = __expf(Av[0] * sdt); ap.y = __expf(Av[1] * sdt);
  ap.z = __expf(Av[2] * sdt); ap.w = __expf(Av[3] * sdt);
  *(float4*)&aprod[base] = ap;
}

// ---------------------------------------------------------------------------
// Kernel: sequential prefix over chunks, IN-PLACE (hs: hloc in, hinit out)
// ---------------------------------------------------------------------------
__global__ __launch_bounds__(256) void k_prefix(float* __restrict__ hs,
                                                const float* __restrict__ aprod) {
  const int t = blockIdx.x * 256 + threadIdx.x;  // 8192 = B*E*N
  const int b = t >> 12, dn = t & 4095;
  float h = 0.f;
  #pragma unroll 4
  for (int c = 0; c < kNC; ++c) {
    const size_t idx = ((size_t)b * kNC + c) * 4096 + dn;
    const float hl = hs[idx];
    const float ap = aprod[idx];
    hs[idx] = h;
    h = fmaf(ap, h, hl);
  }
}

// ---------------------------------------------------------------------------
// Kernel: scan phase C — real scan with init, y = sum_n h*C,
//           fused gating: yT = (y + xc*D) * silu(z).  C rows: bcT 16..31.
// ---------------------------------------------------------------------------
__global__ __launch_bounds__(256) void k_scanC(const float* __restrict__ dtT,
                                               const float* __restrict__ xcT,
                                               const float* __restrict__ bcT,
                                               const float* __restrict__ zT,
                                               const float* __restrict__ A_log,
                                               const float* __restrict__ Dp,
                                               const float* __restrict__ hinit,
                                               float* __restrict__ yT) {
  __shared__ float dtt[64 * 68];
  __shared__ float xct[64 * 68];
  __shared__ float yt[64 * 68];
  __shared__ float Bmt[16 * 68];
  __shared__ float Cmt[16 * 68];
  const int b  = blockIdx.z;
  const int ch = blockIdx.x;
  const int d0 = blockIdx.y * 64;
  const int l0 = ch * kCL;
  const int tid = threadIdx.x;
  #pragma unroll
  for (int it = 0; it < 4; ++it) {
    const int idx = tid + it * 256;
    const int dd = idx >> 4, l4 = idx & 15;
    *(float4*)&dtt[dd * 68 + 4 * l4] = *(const float4*)&dtT[((size_t)b * kE + d0 + dd) * kL + l0 + 4 * l4];
    *(float4*)&xct[dd * 68 + 4 * l4] = *(const float4*)&xcT[((size_t)b * kE + d0 + dd) * kL + l0 + 4 * l4];
  }
  {
    const int n = tid >> 4, l4 = tid & 15;
    *(float4*)&Bmt[n * 68 + 4 * l4] = *(const float4*)&bcT[((size_t)b * 32 + n) * kL + l0 + 4 * l4];
    *(float4*)&Cmt[n * 68 + 4 * l4] = *(const float4*)&bcT[((size_t)b * 32 + 16 + n) * kL + l0 + 4 * l4];
  }
  __syncthreads();
  const int ds = tid >> 2, ng = tid & 3;
  const int d = d0 + ds;
  float Av[4];
  #pragma unroll
  for (int j = 0; j < 4; ++j) Av[j] = -__expf(A_log[d * kN + 4 * ng + j]);
  const float4 hv = *(const float4*)&hinit[(((size_t)b * kNC + ch) * kE + d) * kN + 4 * ng];
  float h[4] = {hv.x, hv.y, hv.z, hv.w};
  for (int l = 0; l < kCL; ++l) {
    const float dtv = dtt[ds * 68 + l];
    const float dx  = dtv * xct[ds * 68 + l];
    float yp = 0.f;
    #pragma unroll
    for (int j = 0; j < 4; ++j) {
      const float dA = __expf(Av[j] * dtv);
      h[j] = fmaf(dA, h[j], Bmt[(4 * ng + j) * 68 + l] * dx);
      yp = fmaf(h[j], Cmt[(4 * ng + j) * 68 + l], yp);
    }
    yp += __shfl_xor(yp, 1);
    yp += __shfl_xor(yp, 2);
    if (ng == 0) yt[ds * 68 + l] = yp;
  }
  __syncthreads();
  #pragma unroll
  for (int it = 0; it < 4; ++it) {
    const int idx = tid + it * 256;
    const int dd = idx >> 4, l4 = idx & 15;
    const float4 yv = *(const float4*)&yt[dd * 68 + 4 * l4];
    const float4 xv = *(const float4*)&xct[dd * 68 + 4 * l4];
    const float4 zv = *(const float4*)&zT[((size_t)b * kE + d0 + dd) * kL + l0 + 4 * l4];
    const float Dv = Dp[d0 + dd];
    float4 o;
    o.x = fmaf(xv.x, Dv, yv.x) * silu(zv.x);
    o.y = fmaf(xv.y, Dv, yv.y) * silu(zv.y);
    o.z = fmaf(xv.z, Dv, yv.z) * silu(zv.z);
    o.w = fmaf(xv.w, Dv, yv.w) * silu(zv.w);
    *(float4*)&yT[((size_t)b * kE + d0 + dd) * kL + l0 + 4 * l4] = o;
  }
}

// ---------------------------------------------------------------------------
extern "C" void kernel_launch(void* const* d_in, const int* in_sizes, int n_in,
                              void* d_out, int out_size, void* d_ws, size_t ws_size,
                              hipStream_t stream) {
  (void)in_sizes; (void)n_in; (void)out_size; (void)ws_size;
  const float* x      = (const float*)d_in[0];
  const float* ln_w   = (const float*)d_in[1];
  const float* ln_b   = (const float*)d_in[2];
  const float* W_in   = (const float*)d_in[3];
  const float* conv_w = (const float*)d_in[4];
  const float* conv_b = (const float*)d_in[5];
  const float* W_x    = (const float*)d_in[6];
  const float* W_dt   = (const float*)d_in[7];
  const float* b_dt   = (const float*)d_in[8];
  const float* A_log  = (const float*)d_in[9];
  const float* Dp     = (const float*)d_in[10];
  const float* W_out  = (const float*)d_in[11];
  float* out = (float*)d_out;
  float* ws  = (float*)d_ws;

  // workspace layout (floats), total 19,603,456 = ~78.4 MB
  float* xiT    = ws;                  // 4,194,304 [b][256][L] (reused as yT)
  float* zT     = ws + 4194304;        // 4,194,304
  float* xcT    = ws + 8388608;        // 4,194,304
  float* dtT    = ws + 12582912;       // 4,194,304
  float* bcT    = ws + 16777216;       //   524,288 [b][32][L] (B rows 0..15, C rows 16..31)
  float* hloc   = ws + 17301504;       // 1,048,576 (in-place -> hinit)
  float* aprod  = ws + 18350080;       // 1,048,576
  float* muA    = ws + 19398656;       //    16,384
  float* rsA    = ws + 19415040;       //    16,384
  float* W_inT  = ws + 19431424;       //    65,536 [128][512]
  float* WcatT  = ws + 19496960;       //    73,728 [256][288]
  float* W_outT = ws + 19570688;       //    32,768 [256][128]
  float* yT     = xiT;                 // xiT dead after conv

  k_prep <<<41, 256, 0, stream>>>(W_in, W_x, W_dt, W_out, W_inT, WcatT, W_outT);
  k_stats<<<dim3(kL / 64, kB), 256, 0, stream>>>(x, muA, rsA);
  k_gemm_sw<128, 512, 64, 512, 0><<<dim3(kL / 256, 8, kB), 256, 0, stream>>>(
      x, W_inT, muA, rsA, ln_w, ln_b, nullptr, xiT, zT);
  k_conv <<<kB * kE * (kL / 16) / 256, 256, 0, stream>>>(xiT, conv_w, conv_b, xcT);
  k_gemm_sw<256, 288, 32, 288, 1><<<dim3(kL / 256, 9, kB), 256, 0, stream>>>(
      xcT, WcatT, nullptr, nullptr, nullptr, nullptr, b_dt, dtT, bcT);
  k_scanA<<<dim3(kNC, kE / 64, kB), 256, 0, stream>>>(dtT, xcT, bcT, A_log, hloc, aprod);
  k_prefix<<<kB * kE * kN / 256, 256, 0, stream>>>(hloc, aprod);
  k_scanC<<<dim3(kNC, kE / 64, kB), 256, 0, stream>>>(dtT, xcT, bcT, zT, A_log, Dp, hloc, yT);
  k_gemm_sw<256, 128, 32, 128, 2><<<dim3(kL / 256, 4, kB), 256, 0, stream>>>(
      yT, W_outT, nullptr, nullptr, nullptr, nullptr, nullptr, out, nullptr);
}

// Round 4
// 178.078 us; speedup vs baseline: 2.3414x; 1.2069x over previous
//
#include <hip/hip_runtime.h>

// Problem constants
constexpr int kB  = 2;
constexpr int kL  = 8192;   // d*h*w = 8*32*32
constexpr int kC  = 128;    // D_MODEL
constexpr int kE  = 256;    // D_INNER
constexpr int kN  = 16;     // D_STATE
constexpr int kCL = 64;     // scan chunk length
constexpr int kNC = kL / kCL; // 128 chunks per batch

typedef __attribute__((ext_vector_type(8))) short bf16x8;
typedef __attribute__((ext_vector_type(4))) float f32x4;
typedef __attribute__((ext_vector_type(8))) unsigned short u16x8;

__device__ __forceinline__ float silu(float v) { return v / (1.f + __expf(-v)); }
__device__ __forceinline__ float softplusf(float s) {
  return fmaxf(s, 0.f) + log1pf(__expf(-fabsf(s)));
}
__device__ __forceinline__ unsigned short f2bf(float x) {
  unsigned u = __float_as_uint(x);
  u += 0x7FFF + ((u >> 16) & 1);
  return (unsigned short)(u >> 16);
}

// ---------------------------------------------------------------------------
// Kernel: weight prep -> bf16 A-frag blobs.
// Frag layout (verified m89/m97): A[m][k], lane: m = lane&15, k = (lane>>4)*8+j.
// blob[( (mt*KS + ks)*64 + lane )*8 + j] = W[mt*16 + (lane&15)][ks*32 + (lane>>4)*8 + j]
//  WinF : W_in   (M=512, K=128)  -> 8192 lane-frags
//  WcatF: m<256: Wfold = W_dt @ W_x[0:8]  (dt path) ; m>=256: W_x[8+m-256]
//         (M=288, K=256) -> 9216 lane-frags
//  WoutF: W_out  (M=128, K=256)  -> 4096 lane-frags
// ---------------------------------------------------------------------------
__global__ __launch_bounds__(256) void k_prep(const float* __restrict__ W_in,
                                              const float* __restrict__ W_x,
                                              const float* __restrict__ W_dt,
                                              const float* __restrict__ W_out,
                                              unsigned short* __restrict__ WinF,
                                              unsigned short* __restrict__ WcatF,
                                              unsigned short* __restrict__ WoutF) {
  const int f = blockIdx.x * 256 + threadIdx.x;
  u16x8 o;
  if (f < 8192) {
    const int lane = f & 63, ks = (f >> 6) & 3, mt = f >> 8;
    const int m = mt * 16 + (lane & 15), kb = ks * 32 + ((lane >> 4) << 3);
    #pragma unroll
    for (int j = 0; j < 8; ++j) o[j] = f2bf(W_in[m * 128 + kb + j]);
    *(u16x8*)&WinF[(size_t)f * 8] = o;
  } else if (f < 17408) {
    const int g = f - 8192;
    const int lane = g & 63, ks = (g >> 6) & 7, mt = g >> 9;
    const int m = mt * 16 + (lane & 15), kb = ks * 32 + ((lane >> 4) << 3);
    if (m < 256) {
      #pragma unroll
      for (int j = 0; j < 8; ++j) {
        float s = 0.f;
        #pragma unroll
        for (int r = 0; r < 8; ++r) s = fmaf(W_dt[m * 8 + r], W_x[r * 256 + kb + j], s);
        o[j] = f2bf(s);
      }
    } else {
      #pragma unroll
      for (int j = 0; j < 8; ++j) o[j] = f2bf(W_x[(8 + m - 256) * 256 + kb + j]);
    }
    *(u16x8*)&WcatF[(size_t)g * 8] = o;
  } else {
    const int g = f - 17408;
    const int lane = g & 63, ks = (g >> 6) & 7, mt = g >> 9;
    const int m = mt * 16 + (lane & 15), kb = ks * 32 + ((lane >> 4) << 3);
    #pragma unroll
    for (int j = 0; j < 8; ++j) o[j] = f2bf(W_out[m * 256 + kb + j]);
    *(u16x8*)&WoutF[(size_t)g * 8] = o;
  }
}

// ---------------------------------------------------------------------------
// Kernel: fused LayerNorm -> xnH bf16 token-major [b][l][128]
// ---------------------------------------------------------------------------
__global__ __launch_bounds__(256) void k_ln(const float* __restrict__ x,
                                            const float* __restrict__ ln_w,
                                            const float* __restrict__ ln_b,
                                            unsigned short* __restrict__ xnH) {
  __shared__ float tile[64 * 132];
  __shared__ float smu[64], srs[64];
  const int b = blockIdx.y, l0 = blockIdx.x * 64, tid = threadIdx.x;
  const int cc = tid >> 6, lt = tid & 63;
  const float* xb = x + (size_t)b * kC * kL;
  for (int c0 = 0; c0 < kC; c0 += 4)
    tile[lt * 132 + c0 + cc] = xb[(size_t)(c0 + cc) * kL + l0 + lt];
  __syncthreads();
  const int l = tid >> 2, q = tid & 3;
  float s = 0.f, s2 = 0.f;
  #pragma unroll
  for (int i = 0; i < 32; ++i) {
    const float v = tile[l * 132 + q + 4 * i];
    s += v; s2 += v * v;
  }
  s += __shfl_xor(s, 1);  s2 += __shfl_xor(s2, 1);
  s += __shfl_xor(s, 2);  s2 += __shfl_xor(s2, 2);
  if (q == 0) {
    const float mu = s * (1.f / 128.f);
    const float var = s2 * (1.f / 128.f) - mu * mu;
    smu[l] = mu; srs[l] = rsqrtf(var + 1e-5f);
  }
  __syncthreads();
  #pragma unroll
  for (int it = 0; it < 4; ++it) {
    const int fidx = tid + it * 256;
    const int li = fidx >> 4, c8 = fidx & 15;
    const float4 v0 = *(const float4*)&tile[li * 132 + c8 * 8];
    const float4 v1 = *(const float4*)&tile[li * 132 + c8 * 8 + 4];
    const float4 w0 = *(const float4*)&ln_w[c8 * 8];
    const float4 w1 = *(const float4*)&ln_w[c8 * 8 + 4];
    const float4 b0 = *(const float4*)&ln_b[c8 * 8];
    const float4 b1 = *(const float4*)&ln_b[c8 * 8 + 4];
    const float mu = smu[li], rs = srs[li];
    u16x8 o;
    o[0] = f2bf((v0.x - mu) * rs * w0.x + b0.x);
    o[1] = f2bf((v0.y - mu) * rs * w0.y + b0.y);
    o[2] = f2bf((v0.z - mu) * rs * w0.z + b0.z);
    o[3] = f2bf((v0.w - mu) * rs * w0.w + b0.w);
    o[4] = f2bf((v1.x - mu) * rs * w1.x + b1.x);
    o[5] = f2bf((v1.y - mu) * rs * w1.y + b1.y);
    o[6] = f2bf((v1.z - mu) * rs * w1.z + b1.z);
    o[7] = f2bf((v1.w - mu) * rs * w1.w + b1.w);
    *(u16x8*)&xnH[((size_t)b * kL + l0 + li) * kC + c8 * 8] = o;
  }
}

// ---------------------------------------------------------------------------
// Unified MFMA GEMM: D[m][l] = sum_k W[m][k] * X[l][k],
//   X token-major bf16 [b][l][K], W as prepped frag blob.
// Block: 64 tokens x (M/CT) rows. 4 waves; wave w handles m-tiles w,w+4,...
// VARIANT 0: gemm1 -> rows<256: xiT, rows>=256: zT        (fp32 ch-major)
// VARIANT 1: dbc   -> rows<256: softplus(+b_dt) -> dtT; rows>=256 -> bcT
// VARIANT 2: gemm3 -> out [b][128][L]
// ---------------------------------------------------------------------------
template<int K, int M, int CT, int VARIANT>
__global__ __launch_bounds__(256) void k_mfma(const unsigned short* __restrict__ XH,
                                              const unsigned short* __restrict__ WF,
                                              const float* __restrict__ bdt,
                                              float* __restrict__ out0,
                                              float* __restrict__ out1) {
  constexpr int KS = K / 32;
  constexpr int MT_BLK = M / 16 / CT;
  constexpr int MT_W = (MT_BLK + 3) / 4;
  constexpr int KPAD = K + 8;
  __shared__ unsigned short Xs[64 * KPAD];
  const int b = blockIdx.z, ct = blockIdx.y, l0 = blockIdx.x * 64;
  const int tid = threadIdx.x, lane = tid & 63, w = tid >> 6;
  // stage X tile (straight copy, 16B granules)
  for (int si = tid; si < 64 * K / 8; si += 256) {
    const int l = si / (K / 8), k8 = si % (K / 8);
    *(uint4*)&Xs[l * KPAD + k8 * 8] =
        *(const uint4*)&XH[((size_t)(b * kL + l0 + l)) * K + k8 * 8];
  }
  __syncthreads();
  f32x4 acc[MT_W][4];
  #pragma unroll
  for (int i = 0; i < MT_W; ++i)
    #pragma unroll
    for (int lt = 0; lt < 4; ++lt) acc[i][lt] = (f32x4){0.f, 0.f, 0.f, 0.f};
  const int colo = lane & 15, kgrp = (lane >> 4) * 8;
  for (int ks = 0; ks < KS; ++ks) {
    bf16x8 Bf[4];
    #pragma unroll
    for (int lt = 0; lt < 4; ++lt)
      Bf[lt] = *(const bf16x8*)&Xs[(lt * 16 + colo) * KPAD + ks * 32 + kgrp];
    #pragma unroll
    for (int i = 0; i < MT_W; ++i) {
      const int mt = w + 4 * i;
      if (mt < MT_BLK) {
        const int mt_g = ct * MT_BLK + mt;
        const bf16x8 Af = *(const bf16x8*)&WF[(size_t)((mt_g * KS + ks) * 64 + lane) * 8];
        #pragma unroll
        for (int lt = 0; lt < 4; ++lt)
          acc[i][lt] = __builtin_amdgcn_mfma_f32_16x16x32_bf16(Af, Bf[lt], acc[i][lt], 0, 0, 0);
      }
    }
  }
  // epilogue: D col = lane&15 (token), row = (lane>>4)*4 + r  (verified m89)
  #pragma unroll
  for (int i = 0; i < MT_W; ++i) {
    const int mt = w + 4 * i;
    if (mt >= MT_BLK) continue;
    const int mbase = (ct * MT_BLK + mt) * 16 + (lane >> 4) * 4;
    #pragma unroll
    for (int r = 0; r < 4; ++r) {
      const int m = mbase + r;
      #pragma unroll
      for (int lt = 0; lt < 4; ++lt) {
        const int lg = l0 + lt * 16 + colo;
        const float v = acc[i][lt][r];
        if (VARIANT == 0) {
          if (m < 256) out0[((size_t)b * kE + m) * kL + lg] = v;
          else         out1[((size_t)b * kE + m - 256) * kL + lg] = v;
        } else if (VARIANT == 1) {
          if (m < 256) out0[((size_t)b * kE + m) * kL + lg] = softplusf(v + bdt[m]);
          else         out1[((size_t)b * 32 + m - 256) * kL + lg] = v;
        } else {
          out0[((size_t)b * kC + m) * kL + lg] = v;
        }
      }
    }
  }
}

// ---------------------------------------------------------------------------
// Kernel: depthwise causal conv + silu.
// xiT fp32 [b][e][L] -> xcT fp32 [b][e][L] + xcH bf16 token-major [b][l][256]
// ---------------------------------------------------------------------------
__global__ __launch_bounds__(256) void k_conv(const float* __restrict__ xiT,
                                              const float* __restrict__ conv_w,
                                              const float* __restrict__ conv_b,
                                              float* __restrict__ xcT,
                                              unsigned short* __restrict__ xcH) {
  const int t = blockIdx.x * 256 + threadIdx.x;   // B*E*(L/16) = 262144
  const int ci  = t & 511;
  const int row = t >> 9;                         // b*256+e
  const int e   = row & 255;
  const int bb  = row >> 8;
  const float4 cw = ((const float4*)conv_w)[e];
  const float cb = conv_b[e];
  const size_t base = (size_t)row * kL + ci * 16;
  const float4* src = (const float4*)(xiT + base);
  float xb[20];
  if (ci) {
    const float4 p = src[-1];
    xb[0] = p.x; xb[1] = p.y; xb[2] = p.z; xb[3] = p.w;
  } else {
    xb[0] = xb[1] = xb[2] = xb[3] = 0.f;
  }
  #pragma unroll
  for (int m = 0; m < 4; ++m) {
    const float4 v = src[m];
    xb[4 + 4 * m] = v.x; xb[5 + 4 * m] = v.y; xb[6 + 4 * m] = v.z; xb[7 + 4 * m] = v.w;
  }
  float4* dst = (float4*)(xcT + base);
  #pragma unroll
  for (int m = 0; m < 4; ++m) {
    float o[4];
    #pragma unroll
    for (int i = 0; i < 4; ++i) {
      const int p = 4 * m + i;
      float s = cb + cw.x * xb[p + 1] + cw.y * xb[p + 2] + cw.z * xb[p + 3] + cw.w * xb[p + 4];
      o[i] = silu(s);
    }
    float4 ov; ov.x = o[0]; ov.y = o[1]; ov.z = o[2]; ov.w = o[3];
    dst[m] = ov;
    #pragma unroll
    for (int i = 0; i < 4; ++i)
      xcH[((size_t)bb * kL + ci * 16 + 4 * m + i) * kE + e] = f2bf(o[i]);
  }
}

// ---------------------------------------------------------------------------
// Kernel: scan phase A — per-chunk local scan (zero init) + chunk product
// ---------------------------------------------------------------------------
__global__ __launch_bounds__(256) void k_scanA(const float* __restrict__ dtT,
                                               const float* __restrict__ xcT,
                                               const float* __restrict__ bcT,
                                               const float* __restrict__ A_log,
                                               float* __restrict__ hloc,
                                               float* __restrict__ aprod) {
  __shared__ float dtt[64 * 68];
  __shared__ float xct[64 * 68];
  __shared__ float Bmt[16 * 68];
  const int b  = blockIdx.z;
  const int ch = blockIdx.x;
  const int d0 = blockIdx.y * 64;
  const int l0 = ch * kCL;
  const int tid = threadIdx.x;
  #pragma unroll
  for (int it = 0; it < 4; ++it) {
    const int idx = tid + it * 256;
    const int dd = idx >> 4, l4 = idx & 15;
    *(float4*)&dtt[dd * 68 + 4 * l4] = *(const float4*)&dtT[((size_t)b * kE + d0 + dd) * kL + l0 + 4 * l4];
    *(float4*)&xct[dd * 68 + 4 * l4] = *(const float4*)&xcT[((size_t)b * kE + d0 + dd) * kL + l0 + 4 * l4];
  }
  {
    const int n = tid >> 4, l4 = tid & 15;
    *(float4*)&Bmt[n * 68 + 4 * l4] = *(const float4*)&bcT[((size_t)b * 32 + n) * kL + l0 + 4 * l4];
  }
  __syncthreads();
  const int ds = tid >> 2, ng = tid & 3;
  const int d = d0 + ds;
  float Av[4];
  #pragma unroll
  for (int j = 0; j < 4; ++j) Av[j] = -__expf(A_log[d * kN + 4 * ng + j]);
  float h[4] = {0.f, 0.f, 0.f, 0.f};
  float sdt = 0.f;
  for (int l = 0; l < kCL; ++l) {
    const float dtv = dtt[ds * 68 + l];
    const float dx  = dtv * xct[ds * 68 + l];
    sdt += dtv;
    #pragma unroll
    for (int j = 0; j < 4; ++j) {
      const float dA = __expf(Av[j] * dtv);
      h[j] = fmaf(dA, h[j], Bmt[(4 * ng + j) * 68 + l] * dx);
    }
  }
  const size_t base = (((size_t)b * kNC + ch) * kE + d) * kN + 4 * ng;
  float4 hv; hv.x = h[0]; hv.y = h[1]; hv.z = h[2]; hv.w = h[3];
  *(float4*)&hloc[base] = hv;
  float4 ap;
  ap.x = __expf(Av[0] * sdt); ap.y = __expf(Av[1] * sdt);
  ap.z = __expf(Av[2] * sdt); ap.w = __expf(Av[3] * sdt);
  *(float4*)&aprod[base] = ap;
}

// ---------------------------------------------------------------------------
// Kernel: sequential prefix over chunks, IN-PLACE (hs: hloc in, hinit out)
// ---------------------------------------------------------------------------
__global__ __launch_bounds__(256) void k_prefix(float* __restrict__ hs,
                                                const float* __restrict__ aprod) {
  const int t = blockIdx.x * 256 + threadIdx.x;  // 8192 = B*E*N
  const int b = t >> 12, dn = t & 4095;
  float h = 0.f;
  #pragma unroll 4
  for (int c = 0; c < kNC; ++c) {
    const size_t idx = ((size_t)b * kNC + c) * 4096 + dn;
    const float hl = hs[idx];
    const float ap = aprod[idx];
    hs[idx] = h;
    h = fmaf(ap, h, hl);
  }
}

// ---------------------------------------------------------------------------
// Kernel: scan phase C — scan with init, y = sum_n h*C, fused gating,
//         emits yH bf16 token-major [b][l][256] for gemm3.
// ---------------------------------------------------------------------------
__global__ __launch_bounds__(256) void k_scanC(const float* __restrict__ dtT,
                                               const float* __restrict__ xcT,
                                               const float* __restrict__ bcT,
                                               const float* __restrict__ zT,
                                               const float* __restrict__ A_log,
                                               const float* __restrict__ Dp,
                                               const float* __restrict__ hinit,
                                               unsigned short* __restrict__ yH) {
  __shared__ float dtt[64 * 68];
  __shared__ float xct[64 * 68];
  __shared__ float yt[64 * 68];
  __shared__ float Bmt[16 * 68];
  __shared__ float Cmt[16 * 68];
  const int b  = blockIdx.z;
  const int ch = blockIdx.x;
  const int d0 = blockIdx.y * 64;
  const int l0 = ch * kCL;
  const int tid = threadIdx.x;
  #pragma unroll
  for (int it = 0; it < 4; ++it) {
    const int idx = tid + it * 256;
    const int dd = idx >> 4, l4 = idx & 15;
    *(float4*)&dtt[dd * 68 + 4 * l4] = *(const float4*)&dtT[((size_t)b * kE + d0 + dd) * kL + l0 + 4 * l4];
    *(float4*)&xct[dd * 68 + 4 * l4] = *(const float4*)&xcT[((size_t)b * kE + d0 + dd) * kL + l0 + 4 * l4];
  }
  {
    const int n = tid >> 4, l4 = tid & 15;
    *(float4*)&Bmt[n * 68 + 4 * l4] = *(const float4*)&bcT[((size_t)b * 32 + n) * kL + l0 + 4 * l4];
    *(float4*)&Cmt[n * 68 + 4 * l4] = *(const float4*)&bcT[((size_t)b * 32 + 16 + n) * kL + l0 + 4 * l4];
  }
  __syncthreads();
  const int ds = tid >> 2, ng = tid & 3;
  const int d = d0 + ds;
  float Av[4];
  #pragma unroll
  for (int j = 0; j < 4; ++j) Av[j] = -__expf(A_log[d * kN + 4 * ng + j]);
  const float4 hv = *(const float4*)&hinit[(((size_t)b * kNC + ch) * kE + d) * kN + 4 * ng];
  float h[4] = {hv.x, hv.y, hv.z, hv.w};
  for (int l = 0; l < kCL; ++l) {
    const float dtv = dtt[ds * 68 + l];
    const float dx  = dtv * xct[ds * 68 + l];
    float yp = 0.f;
    #pragma unroll
    for (int j = 0; j < 4; ++j) {
      const float dA = __expf(Av[j] * dtv);
      h[j] = fmaf(dA, h[j], Bmt[(4 * ng + j) * 68 + l] * dx);
      yp = fmaf(h[j], Cmt[(4 * ng + j) * 68 + l], yp);
    }
    yp += __shfl_xor(yp, 1);
    yp += __shfl_xor(yp, 2);
    if (ng == 0) yt[ds * 68 + l] = yp;
  }
  __syncthreads();
  #pragma unroll
  for (int it = 0; it < 4; ++it) {
    const int idx = tid + it * 256;
    const int dd = idx >> 4, l4 = idx & 15;
    const float4 yv = *(const float4*)&yt[dd * 68 + 4 * l4];
    const float4 xv = *(const float4*)&xct[dd * 68 + 4 * l4];
    const float4 zv = *(const float4*)&zT[((size_t)b * kE + d0 + dd) * kL + l0 + 4 * l4];
    const float Dv = Dp[d0 + dd];
    float o0 = fmaf(xv.x, Dv, yv.x) * silu(zv.x);
    float o1 = fmaf(xv.y, Dv, yv.y) * silu(zv.y);
    float o2 = fmaf(xv.z, Dv, yv.z) * silu(zv.z);
    float o3 = fmaf(xv.w, Dv, yv.w) * silu(zv.w);
    const size_t lb = (size_t)b * kL + l0 + 4 * l4;
    yH[(lb + 0) * kE + d0 + dd] = f2bf(o0);
    yH[(lb + 1) * kE + d0 + dd] = f2bf(o1);
    yH[(lb + 2) * kE + d0 + dd] = f2bf(o2);
    yH[(lb + 3) * kE + d0 + dd] = f2bf(o3);
  }
}

// ---------------------------------------------------------------------------
extern "C" void kernel_launch(void* const* d_in, const int* in_sizes, int n_in,
                              void* d_out, int out_size, void* d_ws, size_t ws_size,
                              hipStream_t stream) {
  (void)in_sizes; (void)n_in; (void)out_size; (void)ws_size;
  const float* x      = (const float*)d_in[0];
  const float* ln_w   = (const float*)d_in[1];
  const float* ln_b   = (const float*)d_in[2];
  const float* W_in   = (const float*)d_in[3];
  const float* conv_w = (const float*)d_in[4];
  const float* conv_b = (const float*)d_in[5];
  const float* W_x    = (const float*)d_in[6];
  const float* W_dt   = (const float*)d_in[7];
  const float* b_dt   = (const float*)d_in[8];
  const float* A_log  = (const float*)d_in[9];
  const float* Dp     = (const float*)d_in[10];
  const float* W_out  = (const float*)d_in[11];
  float* out = (float*)d_out;
  float* ws  = (float*)d_ws;

  // workspace layout (float offsets), total ~77.9 MB (<= proven 78.4 MB)
  float* xiT   = ws;                    // 4,194,304 fp32 [b][256][L]; aliased by yH bf16 [b][l][256]
  float* zT    = ws + 4194304;          // 4,194,304
  float* xcT   = ws + 8388608;          // 4,194,304
  float* dtT   = ws + 12582912;         // 4,194,304; alias: xnH bf16 [b][l][128] (dead before dbc)
  float* bcT   = ws + 16777216;         //   524,288 [b][32][L]
  float* hloc  = ws + 17301504;         // 1,048,576 (aliases xcH; xcH dead after dbc)
  float* aprod = ws + 18350080;         // 1,048,576
  unsigned short* xnH  = (unsigned short*)(ws + 12582912);
  unsigned short* xcH  = (unsigned short*)(ws + 17301504);
  unsigned short* yH   = (unsigned short*)(ws);
  unsigned short* WinF = (unsigned short*)(ws + 19398656);  //  65,536 u16
  unsigned short* WcatF = WinF + 65536;                     //  73,728 u16
  unsigned short* WoutF = WinF + 139264;                    //  32,768 u16

  k_prep<<<84, 256, 0, stream>>>(W_in, W_x, W_dt, W_out, WinF, WcatF, WoutF);
  k_ln  <<<dim3(kL / 64, kB), 256, 0, stream>>>(x, ln_w, ln_b, xnH);
  k_mfma<128, 512, 4, 0><<<dim3(kL / 64, 4, kB), 256, 0, stream>>>(xnH, WinF, nullptr, xiT, zT);
  k_conv<<<kB * kE * (kL / 16) / 256, 256, 0, stream>>>(xiT, conv_w, conv_b, xcT, xcH);
  k_mfma<256, 288, 2, 1><<<dim3(kL / 64, 2, kB), 256, 0, stream>>>(xcH, WcatF, b_dt, dtT, bcT);
  k_scanA<<<dim3(kNC, kE / 64, kB), 256, 0, stream>>>(dtT, xcT, bcT, A_log, hloc, aprod);
  k_prefix<<<kB * kE * kN / 256, 256, 0, stream>>>(hloc, aprod);
  k_scanC<<<dim3(kNC, kE / 64, kB), 256, 0, stream>>>(dtT, xcT, bcT, zT, A_log, Dp, hloc, yH);
  k_mfma<256, 128, 1, 2><<<dim3(kL / 64, 1, kB), 256, 0, stream>>>(yH, WoutF, nullptr, out, nullptr);
}

// Round 5
// 162.840 us; speedup vs baseline: 2.5605x; 1.0936x over previous
//
#include <hip/hip_runtime.h>

// Problem constants
constexpr int kB  = 2;
constexpr int kL  = 8192;   // d*h*w = 8*32*32
constexpr int kC  = 128;    // D_MODEL
constexpr int kE  = 256;    // D_INNER
constexpr int kN  = 16;     // D_STATE
constexpr int kCL = 64;     // scan chunk length
constexpr int kNC = kL / kCL; // 128 chunks per batch

typedef __attribute__((ext_vector_type(8))) short bf16x8;
typedef __attribute__((ext_vector_type(4))) float f32x4;
typedef __attribute__((ext_vector_type(8))) unsigned short u16x8;

__device__ __forceinline__ float silu(float v) { return v / (1.f + __expf(-v)); }
__device__ __forceinline__ float softplusf(float s) {
  return fmaxf(s, 0.f) + log1pf(__expf(-fabsf(s)));
}
__device__ __forceinline__ unsigned short f2bf(float x) {
  unsigned u = __float_as_uint(x);
  u += 0x7FFF + ((u >> 16) & 1);
  return (unsigned short)(u >> 16);
}

// ---------------------------------------------------------------------------
// Kernel: weight prep -> bf16 A-frag blobs (verified m89/m97 layout).
// ---------------------------------------------------------------------------
__global__ __launch_bounds__(256) void k_prep(const float* __restrict__ W_in,
                                              const float* __restrict__ W_x,
                                              const float* __restrict__ W_dt,
                                              const float* __restrict__ W_out,
                                              unsigned short* __restrict__ WinF,
                                              unsigned short* __restrict__ WcatF,
                                              unsigned short* __restrict__ WoutF) {
  const int f = blockIdx.x * 256 + threadIdx.x;
  u16x8 o;
  if (f < 8192) {
    const int lane = f & 63, ks = (f >> 6) & 3, mt = f >> 8;
    const int m = mt * 16 + (lane & 15), kb = ks * 32 + ((lane >> 4) << 3);
    #pragma unroll
    for (int j = 0; j < 8; ++j) o[j] = f2bf(W_in[m * 128 + kb + j]);
    *(u16x8*)&WinF[(size_t)f * 8] = o;
  } else if (f < 17408) {
    const int g = f - 8192;
    const int lane = g & 63, ks = (g >> 6) & 7, mt = g >> 9;
    const int m = mt * 16 + (lane & 15), kb = ks * 32 + ((lane >> 4) << 3);
    if (m < 256) {
      #pragma unroll
      for (int j = 0; j < 8; ++j) {
        float s = 0.f;
        #pragma unroll
        for (int r = 0; r < 8; ++r) s = fmaf(W_dt[m * 8 + r], W_x[r * 256 + kb + j], s);
        o[j] = f2bf(s);
      }
    } else {
      #pragma unroll
      for (int j = 0; j < 8; ++j) o[j] = f2bf(W_x[(8 + m - 256) * 256 + kb + j]);
    }
    *(u16x8*)&WcatF[(size_t)g * 8] = o;
  } else {
    const int g = f - 17408;
    const int lane = g & 63, ks = (g >> 6) & 7, mt = g >> 9;
    const int m = mt * 16 + (lane & 15), kb = ks * 32 + ((lane >> 4) << 3);
    #pragma unroll
    for (int j = 0; j < 8; ++j) o[j] = f2bf(W_out[m * 256 + kb + j]);
    *(u16x8*)&WoutF[(size_t)g * 8] = o;
  }
}

// ---------------------------------------------------------------------------
// Kernel: fused LayerNorm -> xnH bf16 token-major [b][l][128]
// ---------------------------------------------------------------------------
__global__ __launch_bounds__(256) void k_ln(const float* __restrict__ x,
                                            const float* __restrict__ ln_w,
                                            const float* __restrict__ ln_b,
                                            unsigned short* __restrict__ xnH) {
  __shared__ float tile[64 * 132];
  __shared__ float smu[64], srs[64];
  const int b = blockIdx.y, l0 = blockIdx.x * 64, tid = threadIdx.x;
  const int cc = tid >> 6, lt = tid & 63;
  const float* xb = x + (size_t)b * kC * kL;
  for (int c0 = 0; c0 < kC; c0 += 4)
    tile[lt * 132 + c0 + cc] = xb[(size_t)(c0 + cc) * kL + l0 + lt];
  __syncthreads();
  const int l = tid >> 2, q = tid & 3;
  float s = 0.f, s2 = 0.f;
  #pragma unroll
  for (int i = 0; i < 32; ++i) {
    const float v = tile[l * 132 + q + 4 * i];
    s += v; s2 += v * v;
  }
  s += __shfl_xor(s, 1);  s2 += __shfl_xor(s2, 1);
  s += __shfl_xor(s, 2);  s2 += __shfl_xor(s2, 2);
  if (q == 0) {
    const float mu = s * (1.f / 128.f);
    const float var = s2 * (1.f / 128.f) - mu * mu;
    smu[l] = mu; srs[l] = rsqrtf(var + 1e-5f);
  }
  __syncthreads();
  #pragma unroll
  for (int it = 0; it < 4; ++it) {
    const int fidx = tid + it * 256;
    const int li = fidx >> 4, c8 = fidx & 15;
    const float4 v0 = *(const float4*)&tile[li * 132 + c8 * 8];
    const float4 v1 = *(const float4*)&tile[li * 132 + c8 * 8 + 4];
    const float4 w0 = *(const float4*)&ln_w[c8 * 8];
    const float4 w1 = *(const float4*)&ln_w[c8 * 8 + 4];
    const float4 b0 = *(const float4*)&ln_b[c8 * 8];
    const float4 b1 = *(const float4*)&ln_b[c8 * 8 + 4];
    const float mu = smu[li], rs = srs[li];
    u16x8 o;
    o[0] = f2bf((v0.x - mu) * rs * w0.x + b0.x);
    o[1] = f2bf((v0.y - mu) * rs * w0.y + b0.y);
    o[2] = f2bf((v0.z - mu) * rs * w0.z + b0.z);
    o[3] = f2bf((v0.w - mu) * rs * w0.w + b0.w);
    o[4] = f2bf((v1.x - mu) * rs * w1.x + b1.x);
    o[5] = f2bf((v1.y - mu) * rs * w1.y + b1.y);
    o[6] = f2bf((v1.z - mu) * rs * w1.z + b1.z);
    o[7] = f2bf((v1.w - mu) * rs * w1.w + b1.w);
    *(u16x8*)&xnH[((size_t)b * kL + l0 + li) * kC + c8 * 8] = o;
  }
}

// ---------------------------------------------------------------------------
// Unified MFMA GEMM (unchanged from round 4).
// ---------------------------------------------------------------------------
template<int K, int M, int CT, int VARIANT>
__global__ __launch_bounds__(256) void k_mfma(const unsigned short* __restrict__ XH,
                                              const unsigned short* __restrict__ WF,
                                              const float* __restrict__ bdt,
                                              float* __restrict__ out0,
                                              float* __restrict__ out1) {
  constexpr int KS = K / 32;
  constexpr int MT_BLK = M / 16 / CT;
  constexpr int MT_W = (MT_BLK + 3) / 4;
  constexpr int KPAD = K + 8;
  __shared__ unsigned short Xs[64 * KPAD];
  const int b = blockIdx.z, ct = blockIdx.y, l0 = blockIdx.x * 64;
  const int tid = threadIdx.x, lane = tid & 63, w = tid >> 6;
  for (int si = tid; si < 64 * K / 8; si += 256) {
    const int l = si / (K / 8), k8 = si % (K / 8);
    *(uint4*)&Xs[l * KPAD + k8 * 8] =
        *(const uint4*)&XH[((size_t)(b * kL + l0 + l)) * K + k8 * 8];
  }
  __syncthreads();
  f32x4 acc[MT_W][4];
  #pragma unroll
  for (int i = 0; i < MT_W; ++i)
    #pragma unroll
    for (int lt = 0; lt < 4; ++lt) acc[i][lt] = (f32x4){0.f, 0.f, 0.f, 0.f};
  const int colo = lane & 15, kgrp = (lane >> 4) * 8;
  for (int ks = 0; ks < KS; ++ks) {
    bf16x8 Bf[4];
    #pragma unroll
    for (int lt = 0; lt < 4; ++lt)
      Bf[lt] = *(const bf16x8*)&Xs[(lt * 16 + colo) * KPAD + ks * 32 + kgrp];
    #pragma unroll
    for (int i = 0; i < MT_W; ++i) {
      const int mt = w + 4 * i;
      if (mt < MT_BLK) {
        const int mt_g = ct * MT_BLK + mt;
        const bf16x8 Af = *(const bf16x8*)&WF[(size_t)((mt_g * KS + ks) * 64 + lane) * 8];
        #pragma unroll
        for (int lt = 0; lt < 4; ++lt)
          acc[i][lt] = __builtin_amdgcn_mfma_f32_16x16x32_bf16(Af, Bf[lt], acc[i][lt], 0, 0, 0);
      }
    }
  }
  #pragma unroll
  for (int i = 0; i < MT_W; ++i) {
    const int mt = w + 4 * i;
    if (mt >= MT_BLK) continue;
    const int mbase = (ct * MT_BLK + mt) * 16 + (lane >> 4) * 4;
    #pragma unroll
    for (int r = 0; r < 4; ++r) {
      const int m = mbase + r;
      #pragma unroll
      for (int lt = 0; lt < 4; ++lt) {
        const int lg = l0 + lt * 16 + colo;
        const float v = acc[i][lt][r];
        if (VARIANT == 0) {
          if (m < 256) out0[((size_t)b * kE + m) * kL + lg] = v;
          else         out1[((size_t)b * kE + m - 256) * kL + lg] = v;
        } else if (VARIANT == 1) {
          if (m < 256) out0[((size_t)b * kE + m) * kL + lg] = softplusf(v + bdt[m]);
          else         out1[((size_t)b * 32 + m - 256) * kL + lg] = v;
        } else {
          out0[((size_t)b * kC + m) * kL + lg] = v;
        }
      }
    }
  }
}

// ---------------------------------------------------------------------------
// Kernel: depthwise causal conv + silu, tiled 64e x 64l.
// writes xcT fp32 [b][e][L] (coalesced) + xcH bf16 token-major via LDS
// transpose (coalesced u16x8 stores).
// ---------------------------------------------------------------------------
__global__ __launch_bounds__(256) void k_conv(const float* __restrict__ xiT,
                                              const float* __restrict__ conv_w,
                                              const float* __restrict__ conv_b,
                                              float* __restrict__ xcT,
                                              unsigned short* __restrict__ xcH) {
  __shared__ unsigned short ht[64 * 72];   // [e][l] bf16, pad 72
  const int b = blockIdx.z, e0 = blockIdx.y * 64, l0 = blockIdx.x * 64;
  const int tid = threadIdx.x;
  const int e = tid >> 2, q = tid & 3;
  const int ge = e0 + e;
  const float4 cw = ((const float4*)conv_w)[ge];
  const float cb = conv_b[ge];
  const size_t base = ((size_t)b * kE + ge) * kL + l0 + q * 16;
  const float4* src = (const float4*)(xiT + base);
  float xb[20];
  if (l0 + q * 16) {
    const float4 p = src[-1];
    xb[0] = p.x; xb[1] = p.y; xb[2] = p.z; xb[3] = p.w;
  } else {
    xb[0] = xb[1] = xb[2] = xb[3] = 0.f;
  }
  #pragma unroll
  for (int m = 0; m < 4; ++m) {
    const float4 v = src[m];
    xb[4 + 4 * m] = v.x; xb[5 + 4 * m] = v.y; xb[6 + 4 * m] = v.z; xb[7 + 4 * m] = v.w;
  }
  float o[16];
  #pragma unroll
  for (int p = 0; p < 16; ++p) {
    float s = cb + cw.x * xb[p + 1] + cw.y * xb[p + 2] + cw.z * xb[p + 3] + cw.w * xb[p + 4];
    o[p] = silu(s);
  }
  float4* dst = (float4*)(xcT + base);
  #pragma unroll
  for (int m = 0; m < 4; ++m) {
    float4 ov; ov.x = o[4 * m]; ov.y = o[4 * m + 1]; ov.z = o[4 * m + 2]; ov.w = o[4 * m + 3];
    dst[m] = ov;
  }
  u16x8 h0, h1;
  #pragma unroll
  for (int i = 0; i < 8; ++i) { h0[i] = f2bf(o[i]); h1[i] = f2bf(o[8 + i]); }
  *(u16x8*)&ht[e * 72 + q * 16]     = h0;
  *(u16x8*)&ht[e * 72 + q * 16 + 8] = h1;
  __syncthreads();
  const int l = tid >> 2, g = tid & 3;
  u16x8 r0, r1;
  #pragma unroll
  for (int i = 0; i < 8; ++i) {
    r0[i] = ht[(g * 16 + i) * 72 + l];
    r1[i] = ht[(g * 16 + 8 + i) * 72 + l];
  }
  unsigned short* orow = &xcH[((size_t)b * kL + l0 + l) * kE + e0 + g * 16];
  *(u16x8*)orow = r0;
  *(u16x8*)(orow + 8) = r1;
}

// ---------------------------------------------------------------------------
// Kernel: scan phase A — 32d x 64l tiles, 2 n-states/thread.
// LDS: interleaved (dt,xc) float2 stream + (B2p,B2p+1) float2 stream.
// ---------------------------------------------------------------------------
__global__ __launch_bounds__(256) void k_scanA(const float* __restrict__ dtT,
                                               const float* __restrict__ xcT,
                                               const float* __restrict__ bcT,
                                               const float* __restrict__ A_log,
                                               float* __restrict__ hloc,
                                               float* __restrict__ aprod) {
  __shared__ float dxi[32 * 70 * 2];   // [dd][l pad70][{dt,xc}]
  __shared__ float Bp[8 * 70 * 2];     // [p][l pad70][{B[2p],B[2p+1]}]
  const int b = blockIdx.z, ch = blockIdx.x, d0 = blockIdx.y * 32;
  const int l0 = ch * kCL, tid = threadIdx.x;
  #pragma unroll
  for (int it = 0; it < 2; ++it) {
    const int idx = tid + it * 256;
    const int dd = idx >> 4, l4 = idx & 15;
    const float4 dv = *(const float4*)&dtT[((size_t)b * kE + d0 + dd) * kL + l0 + 4 * l4];
    const float4 xv = *(const float4*)&xcT[((size_t)b * kE + d0 + dd) * kL + l0 + 4 * l4];
    float* w = &dxi[(dd * 70 + 4 * l4) * 2];
    ((float4*)w)[0] = make_float4(dv.x, xv.x, dv.y, xv.y);
    ((float4*)w)[1] = make_float4(dv.z, xv.z, dv.w, xv.w);
  }
  if (tid < 128) {
    const int p = tid >> 4, l4 = tid & 15;
    const float4 b0 = *(const float4*)&bcT[((size_t)b * 32 + 2 * p) * kL + l0 + 4 * l4];
    const float4 b1 = *(const float4*)&bcT[((size_t)b * 32 + 2 * p + 1) * kL + l0 + 4 * l4];
    float* w = &Bp[(p * 70 + 4 * l4) * 2];
    ((float4*)w)[0] = make_float4(b0.x, b1.x, b0.y, b1.y);
    ((float4*)w)[1] = make_float4(b0.z, b1.z, b0.w, b1.w);
  }
  __syncthreads();
  const int ds = tid >> 3, ng = tid & 7;
  const int d = d0 + ds;
  const float2 Al = *(const float2*)&A_log[d * kN + 2 * ng];
  const float Av0 = -__expf(Al.x), Av1 = -__expf(Al.y);
  float h0 = 0.f, h1 = 0.f, sdt = 0.f;
  const float* drow = &dxi[ds * 140];
  const float* brow = &Bp[ng * 140];
  for (int l = 0; l < kCL; ++l) {
    const float2 dx2 = *(const float2*)&drow[2 * l];
    const float2 bb  = *(const float2*)&brow[2 * l];
    const float dxv = dx2.x * dx2.y;
    sdt += dx2.x;
    h0 = fmaf(__expf(Av0 * dx2.x), h0, bb.x * dxv);
    h1 = fmaf(__expf(Av1 * dx2.x), h1, bb.y * dxv);
  }
  const size_t base = (((size_t)b * kNC + ch) * kE + d) * kN + 2 * ng;
  *(float2*)&hloc[base] = make_float2(h0, h1);
  *(float2*)&aprod[base] = make_float2(__expf(Av0 * sdt), __expf(Av1 * sdt));
}

// ---------------------------------------------------------------------------
// Kernel: sequential prefix over chunks, IN-PLACE (hs: hloc in, hinit out)
// ---------------------------------------------------------------------------
__global__ __launch_bounds__(256) void k_prefix(float* __restrict__ hs,
                                                const float* __restrict__ aprod) {
  const int t = blockIdx.x * 256 + threadIdx.x;  // 8192 = B*E*N
  const int b = t >> 12, dn = t & 4095;
  float h = 0.f;
  #pragma unroll 4
  for (int c = 0; c < kNC; ++c) {
    const size_t idx = ((size_t)b * kNC + c) * 4096 + dn;
    const float hl = hs[idx];
    const float ap = aprod[idx];
    hs[idx] = h;
    h = fmaf(ap, h, hl);
  }
}

// ---------------------------------------------------------------------------
// Kernel: scan phase C — 32d x 64l tiles, 2 n/thread, 8-lane y-reduce,
// fused gating, coalesced yH bf16 token-major output.
// ---------------------------------------------------------------------------
__global__ __launch_bounds__(256) void k_scanC(const float* __restrict__ dtT,
                                               const float* __restrict__ xcT,
                                               const float* __restrict__ bcT,
                                               const float* __restrict__ zT,
                                               const float* __restrict__ A_log,
                                               const float* __restrict__ Dp,
                                               const float* __restrict__ hinit,
                                               unsigned short* __restrict__ yH) {
  __shared__ float dxi[32 * 70 * 2];   // [dd][l pad70][{dt,xc}]
  __shared__ float bc2[16 * 70 * 2];   // [n][l pad70][{B,C}]
  __shared__ float yt[32 * 68];        // [dd][l pad68]
  const int b = blockIdx.z, ch = blockIdx.x, d0 = blockIdx.y * 32;
  const int l0 = ch * kCL, tid = threadIdx.x;
  #pragma unroll
  for (int it = 0; it < 2; ++it) {
    const int idx = tid + it * 256;
    const int dd = idx >> 4, l4 = idx & 15;
    const float4 dv = *(const float4*)&dtT[((size_t)b * kE + d0 + dd) * kL + l0 + 4 * l4];
    const float4 xv = *(const float4*)&xcT[((size_t)b * kE + d0 + dd) * kL + l0 + 4 * l4];
    float* w = &dxi[(dd * 70 + 4 * l4) * 2];
    ((float4*)w)[0] = make_float4(dv.x, xv.x, dv.y, xv.y);
    ((float4*)w)[1] = make_float4(dv.z, xv.z, dv.w, xv.w);
  }
  {
    const int n = tid >> 4, l4 = tid & 15;
    const float4 bv = *(const float4*)&bcT[((size_t)b * 32 + n) * kL + l0 + 4 * l4];
    const float4 cv = *(const float4*)&bcT[((size_t)b * 32 + 16 + n) * kL + l0 + 4 * l4];
    float* w = &bc2[(n * 70 + 4 * l4) * 2];
    ((float4*)w)[0] = make_float4(bv.x, cv.x, bv.y, cv.y);
    ((float4*)w)[1] = make_float4(bv.z, cv.z, bv.w, cv.w);
  }
  __syncthreads();
  const int ds = tid >> 3, ng = tid & 7;
  const int d = d0 + ds;
  const float2 Al = *(const float2*)&A_log[d * kN + 2 * ng];
  const float Av0 = -__expf(Al.x), Av1 = -__expf(Al.y);
  const size_t hbase = (((size_t)b * kNC + ch) * kE + d) * kN + 2 * ng;
  const float2 hv = *(const float2*)&hinit[hbase];
  float h0 = hv.x, h1 = hv.y;
  const float* drow  = &dxi[ds * 140];
  const float* b0row = &bc2[(2 * ng) * 140];
  const float* b1row = &bc2[(2 * ng + 1) * 140];
  for (int l = 0; l < kCL; ++l) {
    const float2 dx2 = *(const float2*)&drow[2 * l];
    const float2 bc0 = *(const float2*)&b0row[2 * l];
    const float2 bc1 = *(const float2*)&b1row[2 * l];
    const float dxv = dx2.x * dx2.y;
    h0 = fmaf(__expf(Av0 * dx2.x), h0, bc0.x * dxv);
    h1 = fmaf(__expf(Av1 * dx2.x), h1, bc1.x * dxv);
    float yp = fmaf(h0, bc0.y, h1 * bc1.y);
    yp += __shfl_xor(yp, 1);
    yp += __shfl_xor(yp, 2);
    yp += __shfl_xor(yp, 4);
    if (ng == 0) yt[ds * 68 + l] = yp;
  }
  __syncthreads();
  // epilogue: (g fast, l slow) -> coalesced token-major u16x8 stores
  const int l = tid >> 2, g = tid & 3;
  u16x8 ov;
  #pragma unroll
  for (int i = 0; i < 8; ++i) {
    const int dd = g * 8 + i;
    const float yv = yt[dd * 68 + l];
    const float xv = dxi[(dd * 70 + l) * 2 + 1];
    const float zv = zT[((size_t)b * kE + d0 + dd) * kL + l0 + l];
    const float o = fmaf(xv, Dp[d0 + dd], yv) * silu(zv);
    ov[i] = f2bf(o);
  }
  *(u16x8*)&yH[((size_t)b * kL + l0 + l) * kE + d0 + g * 8] = ov;
}

// ---------------------------------------------------------------------------
extern "C" void kernel_launch(void* const* d_in, const int* in_sizes, int n_in,
                              void* d_out, int out_size, void* d_ws, size_t ws_size,
                              hipStream_t stream) {
  (void)in_sizes; (void)n_in; (void)out_size; (void)ws_size;
  const float* x      = (const float*)d_in[0];
  const float* ln_w   = (const float*)d_in[1];
  const float* ln_b   = (const float*)d_in[2];
  const float* W_in   = (const float*)d_in[3];
  const float* conv_w = (const float*)d_in[4];
  const float* conv_b = (const float*)d_in[5];
  const float* W_x    = (const float*)d_in[6];
  const float* W_dt   = (const float*)d_in[7];
  const float* b_dt   = (const float*)d_in[8];
  const float* A_log  = (const float*)d_in[9];
  const float* Dp     = (const float*)d_in[10];
  const float* W_out  = (const float*)d_in[11];
  float* out = (float*)d_out;
  float* ws  = (float*)d_ws;

  // workspace layout (float offsets), ~77.9 MB
  float* xiT   = ws;                    // 4,194,304 fp32 [b][256][L]; later aliased by yH
  float* zT    = ws + 4194304;          // 4,194,304
  float* xcT   = ws + 8388608;          // 4,194,304
  float* dtT   = ws + 12582912;         // 4,194,304; alias: xnH bf16 (dead before dbc)
  float* bcT   = ws + 16777216;         //   524,288 [b][32][L]
  float* hloc  = ws + 17301504;         // 1,048,576 (aliases xcH; xcH dead after dbc)
  float* aprod = ws + 18350080;         // 1,048,576
  unsigned short* xnH  = (unsigned short*)(ws + 12582912);
  unsigned short* xcH  = (unsigned short*)(ws + 17301504);
  unsigned short* yH   = (unsigned short*)(ws);
  unsigned short* WinF = (unsigned short*)(ws + 19398656);  //  65,536 u16
  unsigned short* WcatF = WinF + 65536;                     //  73,728 u16
  unsigned short* WoutF = WinF + 139264;                    //  32,768 u16

  k_prep<<<84, 256, 0, stream>>>(W_in, W_x, W_dt, W_out, WinF, WcatF, WoutF);
  k_ln  <<<dim3(kL / 64, kB), 256, 0, stream>>>(x, ln_w, ln_b, xnH);
  k_mfma<128, 512, 4, 0><<<dim3(kL / 64, 4, kB), 256, 0, stream>>>(xnH, WinF, nullptr, xiT, zT);
  k_conv<<<dim3(kL / 64, kE / 64, kB), 256, 0, stream>>>(xiT, conv_w, conv_b, xcT, xcH);
  k_mfma<256, 288, 2, 1><<<dim3(kL / 64, 2, kB), 256, 0, stream>>>(xcH, WcatF, b_dt, dtT, bcT);
  k_scanA<<<dim3(kNC, kE / 32, kB), 256, 0, stream>>>(dtT, xcT, bcT, A_log, hloc, aprod);
  k_prefix<<<kB * kE * kN / 256, 256, 0, stream>>>(hloc, aprod);
  k_scanC<<<dim3(kNC, kE / 32, kB), 256, 0, stream>>>(dtT, xcT, bcT, zT, A_log, Dp, hloc, yH);
  k_mfma<256, 128, 1, 2><<<dim3(kL / 64, 1, kB), 256, 0, stream>>>(yH, WoutF, nullptr, out, nullptr);
}

// Round 6
// 148.025 us; speedup vs baseline: 2.8168x; 1.1001x over previous
//
#include <hip/hip_runtime.h>

// Problem constants
constexpr int kB  = 2;
constexpr int kL  = 8192;   // d*h*w = 8*32*32
constexpr int kC  = 128;    // D_MODEL
constexpr int kE  = 256;    // D_INNER
constexpr int kN  = 16;     // D_STATE
constexpr int kCL = 64;     // scan chunk length
constexpr int kNC = kL / kCL; // 128 chunks per batch

typedef __attribute__((ext_vector_type(8))) short bf16x8;
typedef __attribute__((ext_vector_type(4))) float f32x4;
typedef __attribute__((ext_vector_type(8))) unsigned short u16x8;

__device__ __forceinline__ float silu(float v) { return v / (1.f + __expf(-v)); }
__device__ __forceinline__ float softplusf(float s) {
  return fmaxf(s, 0.f) + log1pf(__expf(-fabsf(s)));
}
__device__ __forceinline__ unsigned short f2bf(float x) {
  unsigned u = __float_as_uint(x);
  u += 0x7FFF + ((u >> 16) & 1);
  return (unsigned short)(u >> 16);
}
// Sum over aligned 8-lane groups entirely on the VALU pipe (DPP), no DS ops.
// quad_perm xor1 (0xB1), quad_perm xor2 (0x4E), row_half_mirror (0x141).
__device__ __forceinline__ float dpp_red8(float v) {
  v += __int_as_float(__builtin_amdgcn_mov_dpp(__float_as_int(v), 0xB1, 0xF, 0xF, true));
  v += __int_as_float(__builtin_amdgcn_mov_dpp(__float_as_int(v), 0x4E, 0xF, 0xF, true));
  v += __int_as_float(__builtin_amdgcn_mov_dpp(__float_as_int(v), 0x141, 0xF, 0xF, true));
  return v;
}

// ---------------------------------------------------------------------------
// Kernel: weight prep -> bf16 A-frag blobs (verified m89/m97 layout).
// ---------------------------------------------------------------------------
__global__ __launch_bounds__(256) void k_prep(const float* __restrict__ W_in,
                                              const float* __restrict__ W_x,
                                              const float* __restrict__ W_dt,
                                              const float* __restrict__ W_out,
                                              unsigned short* __restrict__ WinF,
                                              unsigned short* __restrict__ WcatF,
                                              unsigned short* __restrict__ WoutF) {
  const int f = blockIdx.x * 256 + threadIdx.x;
  u16x8 o;
  if (f < 8192) {
    const int lane = f & 63, ks = (f >> 6) & 3, mt = f >> 8;
    const int m = mt * 16 + (lane & 15), kb = ks * 32 + ((lane >> 4) << 3);
    #pragma unroll
    for (int j = 0; j < 8; ++j) o[j] = f2bf(W_in[m * 128 + kb + j]);
    *(u16x8*)&WinF[(size_t)f * 8] = o;
  } else if (f < 17408) {
    const int g = f - 8192;
    const int lane = g & 63, ks = (g >> 6) & 7, mt = g >> 9;
    const int m = mt * 16 + (lane & 15), kb = ks * 32 + ((lane >> 4) << 3);
    if (m < 256) {
      #pragma unroll
      for (int j = 0; j < 8; ++j) {
        float s = 0.f;
        #pragma unroll
        for (int r = 0; r < 8; ++r) s = fmaf(W_dt[m * 8 + r], W_x[r * 256 + kb + j], s);
        o[j] = f2bf(s);
      }
    } else {
      #pragma unroll
      for (int j = 0; j < 8; ++j) o[j] = f2bf(W_x[(8 + m - 256) * 256 + kb + j]);
    }
    *(u16x8*)&WcatF[(size_t)g * 8] = o;
  } else {
    const int g = f - 17408;
    const int lane = g & 63, ks = (g >> 6) & 7, mt = g >> 9;
    const int m = mt * 16 + (lane & 15), kb = ks * 32 + ((lane >> 4) << 3);
    #pragma unroll
    for (int j = 0; j < 8; ++j) o[j] = f2bf(W_out[m * 256 + kb + j]);
    *(u16x8*)&WoutF[(size_t)g * 8] = o;
  }
}

// ---------------------------------------------------------------------------
// Kernel: fused LayerNorm -> xnH bf16 token-major [b][l][128]
// ---------------------------------------------------------------------------
__global__ __launch_bounds__(256) void k_ln(const float* __restrict__ x,
                                            const float* __restrict__ ln_w,
                                            const float* __restrict__ ln_b,
                                            unsigned short* __restrict__ xnH) {
  __shared__ float tile[64 * 132];
  __shared__ float smu[64], srs[64];
  const int b = blockIdx.y, l0 = blockIdx.x * 64, tid = threadIdx.x;
  const int cc = tid >> 6, lt = tid & 63;
  const float* xb = x + (size_t)b * kC * kL;
  for (int c0 = 0; c0 < kC; c0 += 4)
    tile[lt * 132 + c0 + cc] = xb[(size_t)(c0 + cc) * kL + l0 + lt];
  __syncthreads();
  const int l = tid >> 2, q = tid & 3;
  float s = 0.f, s2 = 0.f;
  #pragma unroll
  for (int i = 0; i < 32; ++i) {
    const float v = tile[l * 132 + q + 4 * i];
    s += v; s2 += v * v;
  }
  s += __shfl_xor(s, 1);  s2 += __shfl_xor(s2, 1);
  s += __shfl_xor(s, 2);  s2 += __shfl_xor(s2, 2);
  if (q == 0) {
    const float mu = s * (1.f / 128.f);
    const float var = s2 * (1.f / 128.f) - mu * mu;
    smu[l] = mu; srs[l] = rsqrtf(var + 1e-5f);
  }
  __syncthreads();
  #pragma unroll
  for (int it = 0; it < 4; ++it) {
    const int fidx = tid + it * 256;
    const int li = fidx >> 4, c8 = fidx & 15;
    const float4 v0 = *(const float4*)&tile[li * 132 + c8 * 8];
    const float4 v1 = *(const float4*)&tile[li * 132 + c8 * 8 + 4];
    const float4 w0 = *(const float4*)&ln_w[c8 * 8];
    const float4 w1 = *(const float4*)&ln_w[c8 * 8 + 4];
    const float4 b0 = *(const float4*)&ln_b[c8 * 8];
    const float4 b1 = *(const float4*)&ln_b[c8 * 8 + 4];
    const float mu = smu[li], rs = srs[li];
    u16x8 o;
    o[0] = f2bf((v0.x - mu) * rs * w0.x + b0.x);
    o[1] = f2bf((v0.y - mu) * rs * w0.y + b0.y);
    o[2] = f2bf((v0.z - mu) * rs * w0.z + b0.z);
    o[3] = f2bf((v0.w - mu) * rs * w0.w + b0.w);
    o[4] = f2bf((v1.x - mu) * rs * w1.x + b1.x);
    o[5] = f2bf((v1.y - mu) * rs * w1.y + b1.y);
    o[6] = f2bf((v1.z - mu) * rs * w1.z + b1.z);
    o[7] = f2bf((v1.w - mu) * rs * w1.w + b1.w);
    *(u16x8*)&xnH[((size_t)b * kL + l0 + li) * kC + c8 * 8] = o;
  }
}

// ---------------------------------------------------------------------------
// Unified MFMA GEMM (unchanged).
// ---------------------------------------------------------------------------
template<int K, int M, int CT, int VARIANT>
__global__ __launch_bounds__(256) void k_mfma(const unsigned short* __restrict__ XH,
                                              const unsigned short* __restrict__ WF,
                                              const float* __restrict__ bdt,
                                              float* __restrict__ out0,
                                              float* __restrict__ out1) {
  constexpr int KS = K / 32;
  constexpr int MT_BLK = M / 16 / CT;
  constexpr int MT_W = (MT_BLK + 3) / 4;
  constexpr int KPAD = K + 8;
  __shared__ unsigned short Xs[64 * KPAD];
  const int b = blockIdx.z, ct = blockIdx.y, l0 = blockIdx.x * 64;
  const int tid = threadIdx.x, lane = tid & 63, w = tid >> 6;
  for (int si = tid; si < 64 * K / 8; si += 256) {
    const int l = si / (K / 8), k8 = si % (K / 8);
    *(uint4*)&Xs[l * KPAD + k8 * 8] =
        *(const uint4*)&XH[((size_t)(b * kL + l0 + l)) * K + k8 * 8];
  }
  __syncthreads();
  f32x4 acc[MT_W][4];
  #pragma unroll
  for (int i = 0; i < MT_W; ++i)
    #pragma unroll
    for (int lt = 0; lt < 4; ++lt) acc[i][lt] = (f32x4){0.f, 0.f, 0.f, 0.f};
  const int colo = lane & 15, kgrp = (lane >> 4) * 8;
  for (int ks = 0; ks < KS; ++ks) {
    bf16x8 Bf[4];
    #pragma unroll
    for (int lt = 0; lt < 4; ++lt)
      Bf[lt] = *(const bf16x8*)&Xs[(lt * 16 + colo) * KPAD + ks * 32 + kgrp];
    #pragma unroll
    for (int i = 0; i < MT_W; ++i) {
      const int mt = w + 4 * i;
      if (mt < MT_BLK) {
        const int mt_g = ct * MT_BLK + mt;
        const bf16x8 Af = *(const bf16x8*)&WF[(size_t)((mt_g * KS + ks) * 64 + lane) * 8];
        #pragma unroll
        for (int lt = 0; lt < 4; ++lt)
          acc[i][lt] = __builtin_amdgcn_mfma_f32_16x16x32_bf16(Af, Bf[lt], acc[i][lt], 0, 0, 0);
      }
    }
  }
  #pragma unroll
  for (int i = 0; i < MT_W; ++i) {
    const int mt = w + 4 * i;
    if (mt >= MT_BLK) continue;
    const int mbase = (ct * MT_BLK + mt) * 16 + (lane >> 4) * 4;
    #pragma unroll
    for (int r = 0; r < 4; ++r) {
      const int m = mbase + r;
      #pragma unroll
      for (int lt = 0; lt < 4; ++lt) {
        const int lg = l0 + lt * 16 + colo;
        const float v = acc[i][lt][r];
        if (VARIANT == 0) {
          if (m < 256) out0[((size_t)b * kE + m) * kL + lg] = v;
          else         out1[((size_t)b * kE + m - 256) * kL + lg] = v;
        } else if (VARIANT == 1) {
          if (m < 256) out0[((size_t)b * kE + m) * kL + lg] = softplusf(v + bdt[m]);
          else         out1[((size_t)b * 32 + m - 256) * kL + lg] = v;
        } else {
          out0[((size_t)b * kC + m) * kL + lg] = v;
        }
      }
    }
  }
}

// ---------------------------------------------------------------------------
// Kernel: depthwise causal conv + silu, tiled 64e x 64l (unchanged).
// ---------------------------------------------------------------------------
__global__ __launch_bounds__(256) void k_conv(const float* __restrict__ xiT,
                                              const float* __restrict__ conv_w,
                                              const float* __restrict__ conv_b,
                                              float* __restrict__ xcT,
                                              unsigned short* __restrict__ xcH) {
  __shared__ unsigned short ht[64 * 72];   // [e][l] bf16, pad 72
  const int b = blockIdx.z, e0 = blockIdx.y * 64, l0 = blockIdx.x * 64;
  const int tid = threadIdx.x;
  const int e = tid >> 2, q = tid & 3;
  const int ge = e0 + e;
  const float4 cw = ((const float4*)conv_w)[ge];
  const float cb = conv_b[ge];
  const size_t base = ((size_t)b * kE + ge) * kL + l0 + q * 16;
  const float4* src = (const float4*)(xiT + base);
  float xb[20];
  if (l0 + q * 16) {
    const float4 p = src[-1];
    xb[0] = p.x; xb[1] = p.y; xb[2] = p.z; xb[3] = p.w;
  } else {
    xb[0] = xb[1] = xb[2] = xb[3] = 0.f;
  }
  #pragma unroll
  for (int m = 0; m < 4; ++m) {
    const float4 v = src[m];
    xb[4 + 4 * m] = v.x; xb[5 + 4 * m] = v.y; xb[6 + 4 * m] = v.z; xb[7 + 4 * m] = v.w;
  }
  float o[16];
  #pragma unroll
  for (int p = 0; p < 16; ++p) {
    float s = cb + cw.x * xb[p + 1] + cw.y * xb[p + 2] + cw.z * xb[p + 3] + cw.w * xb[p + 4];
    o[p] = silu(s);
  }
  float4* dst = (float4*)(xcT + base);
  #pragma unroll
  for (int m = 0; m < 4; ++m) {
    float4 ov; ov.x = o[4 * m]; ov.y = o[4 * m + 1]; ov.z = o[4 * m + 2]; ov.w = o[4 * m + 3];
    dst[m] = ov;
  }
  u16x8 h0, h1;
  #pragma unroll
  for (int i = 0; i < 8; ++i) { h0[i] = f2bf(o[i]); h1[i] = f2bf(o[8 + i]); }
  *(u16x8*)&ht[e * 72 + q * 16]     = h0;
  *(u16x8*)&ht[e * 72 + q * 16 + 8] = h1;
  __syncthreads();
  const int l = tid >> 2, g = tid & 3;
  u16x8 r0, r1;
  #pragma unroll
  for (int i = 0; i < 8; ++i) {
    r0[i] = ht[(g * 16 + i) * 72 + l];
    r1[i] = ht[(g * 16 + 8 + i) * 72 + l];
  }
  unsigned short* orow = &xcH[((size_t)b * kL + l0 + l) * kE + e0 + g * 16];
  *(u16x8*)orow = r0;
  *(u16x8*)(orow + 8) = r1;
}

// ---------------------------------------------------------------------------
// Kernel: scan phase A — b128-packed LDS, no shuffles, 2 DS reads per 2 l.
// dxi [ds][l][{dt,u}] stride 132 ; Bp [ng][l][{B0,B1}] stride 132.
// ---------------------------------------------------------------------------
__global__ __launch_bounds__(256) void k_scanA(const float* __restrict__ dtT,
                                               const float* __restrict__ xcT,
                                               const float* __restrict__ bcT,
                                               const float* __restrict__ A_log,
                                               float* __restrict__ hloc,
                                               float* __restrict__ aprod) {
  __shared__ float dxi[32 * 132];
  __shared__ float Bp[8 * 132];
  const int b = blockIdx.z, ch = blockIdx.x, d0 = blockIdx.y * 32;
  const int l0 = ch * kCL, tid = threadIdx.x;
  {
    const int ds = tid >> 3, ng = tid & 7;
    const float4* dsrc = (const float4*)&dtT[((size_t)b * kE + d0 + ds) * kL + l0 + 8 * ng];
    const float4* xsrc = (const float4*)&xcT[((size_t)b * kE + d0 + ds) * kL + l0 + 8 * ng];
    float* wr = &dxi[ds * 132 + 16 * ng];
    #pragma unroll
    for (int m = 0; m < 2; ++m) {
      const float4 dv = dsrc[m], xv = xsrc[m];
      *(float4*)&wr[8 * m]     = make_float4(dv.x, dv.x * xv.x, dv.y, dv.y * xv.y);
      *(float4*)&wr[8 * m + 4] = make_float4(dv.z, dv.z * xv.z, dv.w, dv.w * xv.w);
    }
  }
  if (tid < 128) {
    const int ng = tid & 7, lq = tid >> 3;     // lq 0..15
    const float4 b0 = *(const float4*)&bcT[((size_t)b * 32 + 2 * ng) * kL + l0 + 4 * lq];
    const float4 b1 = *(const float4*)&bcT[((size_t)b * 32 + 2 * ng + 1) * kL + l0 + 4 * lq];
    float* wr = &Bp[ng * 132 + 8 * lq];
    *(float4*)&wr[0] = make_float4(b0.x, b1.x, b0.y, b1.y);
    *(float4*)&wr[4] = make_float4(b0.z, b1.z, b0.w, b1.w);
  }
  __syncthreads();
  const int ds = tid >> 3, ng = tid & 7;
  const int d = d0 + ds;
  const float2 Al = *(const float2*)&A_log[d * kN + 2 * ng];
  const float Av0 = -__expf(Al.x), Av1 = -__expf(Al.y);
  float h0 = 0.f, h1 = 0.f, sdt = 0.f;
  const float* drow = &dxi[ds * 132];
  const float* brow = &Bp[ng * 132];
  for (int l = 0; l < kCL; l += 2) {
    const float4 du = *(const float4*)&drow[2 * l];   // dt,u @ l ; dt,u @ l+1
    const float4 bb = *(const float4*)&brow[2 * l];   // B0,B1 @ l ; B0,B1 @ l+1
    sdt += du.x + du.z;
    h0 = fmaf(__expf(Av0 * du.x), h0, bb.x * du.y);
    h1 = fmaf(__expf(Av1 * du.x), h1, bb.y * du.y);
    h0 = fmaf(__expf(Av0 * du.z), h0, bb.z * du.w);
    h1 = fmaf(__expf(Av1 * du.z), h1, bb.w * du.w);
  }
  const size_t base = (((size_t)b * kNC + ch) * kE + d) * kN + 2 * ng;
  *(float2*)&hloc[base] = make_float2(h0, h1);
  *(float2*)&aprod[base] = make_float2(__expf(Av0 * sdt), __expf(Av1 * sdt));
}

// ---------------------------------------------------------------------------
// Kernel: sequential prefix over chunks, IN-PLACE (hs: hloc in, hinit out)
// ---------------------------------------------------------------------------
__global__ __launch_bounds__(256) void k_prefix(float* __restrict__ hs,
                                                const float* __restrict__ aprod) {
  const int t = blockIdx.x * 256 + threadIdx.x;  // 8192 = B*E*N
  const int b = t >> 12, dn = t & 4095;
  float h = 0.f;
  #pragma unroll 4
  for (int c = 0; c < kNC; ++c) {
    const size_t idx = ((size_t)b * kNC + c) * 4096 + dn;
    const float hl = hs[idx];
    const float ap = aprod[idx];
    hs[idx] = h;
    h = fmaf(ap, h, hl);
  }
}

// ---------------------------------------------------------------------------
// Kernel: scan phase C — b128-packed LDS, DPP y-reduce (no DS shuffles).
// dxi [ds][l][{dt,u}] stride 132 ; bc4 [ng][l][{B0,C0,B1,C1}] stride 260 ;
// yt [ds][l] stride 70.
// ---------------------------------------------------------------------------
__global__ __launch_bounds__(256) void k_scanC(const float* __restrict__ dtT,
                                               const float* __restrict__ xcT,
                                               const float* __restrict__ bcT,
                                               const float* __restrict__ zT,
                                               const float* __restrict__ A_log,
                                               const float* __restrict__ Dp,
                                               const float* __restrict__ hinit,
                                               unsigned short* __restrict__ yH) {
  __shared__ float dxi[32 * 132];
  __shared__ float bc4[8 * 260];
  __shared__ float yt[32 * 70];
  const int b = blockIdx.z, ch = blockIdx.x, d0 = blockIdx.y * 32;
  const int l0 = ch * kCL, tid = threadIdx.x;
  {
    const int ds = tid >> 3, ng = tid & 7;
    const float4* dsrc = (const float4*)&dtT[((size_t)b * kE + d0 + ds) * kL + l0 + 8 * ng];
    const float4* xsrc = (const float4*)&xcT[((size_t)b * kE + d0 + ds) * kL + l0 + 8 * ng];
    float* wr = &dxi[ds * 132 + 16 * ng];
    #pragma unroll
    for (int m = 0; m < 2; ++m) {
      const float4 dv = dsrc[m], xv = xsrc[m];
      *(float4*)&wr[8 * m]     = make_float4(dv.x, dv.x * xv.x, dv.y, dv.y * xv.y);
      *(float4*)&wr[8 * m + 4] = make_float4(dv.z, dv.z * xv.z, dv.w, dv.w * xv.w);
    }
  }
  if (tid < 128) {
    const int ng = tid & 7, lq = tid >> 3;     // lq 0..15
    const float4 b0 = *(const float4*)&bcT[((size_t)b * 32 + 2 * ng) * kL + l0 + 4 * lq];
    const float4 c0 = *(const float4*)&bcT[((size_t)b * 32 + 16 + 2 * ng) * kL + l0 + 4 * lq];
    const float4 b1 = *(const float4*)&bcT[((size_t)b * 32 + 2 * ng + 1) * kL + l0 + 4 * lq];
    const float4 c1 = *(const float4*)&bcT[((size_t)b * 32 + 17 + 2 * ng) * kL + l0 + 4 * lq];
    float* wr = &bc4[ng * 260 + 16 * lq];
    *(float4*)&wr[0]  = make_float4(b0.x, c0.x, b1.x, c1.x);
    *(float4*)&wr[4]  = make_float4(b0.y, c0.y, b1.y, c1.y);
    *(float4*)&wr[8]  = make_float4(b0.z, c0.z, b1.z, c1.z);
    *(float4*)&wr[12] = make_float4(b0.w, c0.w, b1.w, c1.w);
  }
  __syncthreads();
  const int ds = tid >> 3, ng = tid & 7;
  const int d = d0 + ds;
  const float2 Al = *(const float2*)&A_log[d * kN + 2 * ng];
  const float Av0 = -__expf(Al.x), Av1 = -__expf(Al.y);
  const size_t hbase = (((size_t)b * kNC + ch) * kE + d) * kN + 2 * ng;
  const float2 hv = *(const float2*)&hinit[hbase];
  float h0 = hv.x, h1 = hv.y;
  const float* drow = &dxi[ds * 132];
  const float* brow = &bc4[ng * 260];
  for (int l = 0; l < kCL; l += 2) {
    const float4 du  = *(const float4*)&drow[2 * l];      // dt,u @ l ; dt,u @ l+1
    const float4 bcA = *(const float4*)&brow[4 * l];      // B0,C0,B1,C1 @ l
    const float4 bcB = *(const float4*)&brow[4 * l + 4];  // @ l+1
    h0 = fmaf(__expf(Av0 * du.x), h0, bcA.x * du.y);
    h1 = fmaf(__expf(Av1 * du.x), h1, bcA.z * du.y);
    const float ylo = dpp_red8(fmaf(h0, bcA.y, h1 * bcA.w));
    h0 = fmaf(__expf(Av0 * du.z), h0, bcB.x * du.w);
    h1 = fmaf(__expf(Av1 * du.z), h1, bcB.z * du.w);
    const float yhi = dpp_red8(fmaf(h0, bcB.y, h1 * bcB.w));
    if (ng == 0) *(float2*)&yt[ds * 70 + l] = make_float2(ylo, yhi);
  }
  __syncthreads();
  // epilogue: gating, coalesced token-major u16x8 stores (xc/z from global)
  const int l = tid >> 2, g = tid & 3;
  u16x8 ov;
  #pragma unroll
  for (int i = 0; i < 8; ++i) {
    const int dd = g * 8 + i;
    const float yv = yt[dd * 70 + l];
    const float xv = xcT[((size_t)b * kE + d0 + dd) * kL + l0 + l];
    const float zv = zT[((size_t)b * kE + d0 + dd) * kL + l0 + l];
    const float o = fmaf(xv, Dp[d0 + dd], yv) * silu(zv);
    ov[i] = f2bf(o);
  }
  *(u16x8*)&yH[((size_t)b * kL + l0 + l) * kE + d0 + g * 8] = ov;
}

// ---------------------------------------------------------------------------
extern "C" void kernel_launch(void* const* d_in, const int* in_sizes, int n_in,
                              void* d_out, int out_size, void* d_ws, size_t ws_size,
                              hipStream_t stream) {
  (void)in_sizes; (void)n_in; (void)out_size; (void)ws_size;
  const float* x      = (const float*)d_in[0];
  const float* ln_w   = (const float*)d_in[1];
  const float* ln_b   = (const float*)d_in[2];
  const float* W_in   = (const float*)d_in[3];
  const float* conv_w = (const float*)d_in[4];
  const float* conv_b = (const float*)d_in[5];
  const float* W_x    = (const float*)d_in[6];
  const float* W_dt   = (const float*)d_in[7];
  const float* b_dt   = (const float*)d_in[8];
  const float* A_log  = (const float*)d_in[9];
  const float* Dp     = (const float*)d_in[10];
  const float* W_out  = (const float*)d_in[11];
  float* out = (float*)d_out;
  float* ws  = (float*)d_ws;

  // workspace layout (float offsets), ~77.9 MB
  float* xiT   = ws;                    // 4,194,304 fp32 [b][256][L]; later aliased by yH
  float* zT    = ws + 4194304;          // 4,194,304
  float* xcT   = ws + 8388608;          // 4,194,304
  float* dtT   = ws + 12582912;         // 4,194,304; alias: xnH bf16 (dead before dbc)
  float* bcT   = ws + 16777216;         //   524,288 [b][32][L]
  float* hloc  = ws + 17301504;         // 1,048,576 (aliases xcH; xcH dead after dbc)
  float* aprod = ws + 18350080;         // 1,048,576
  unsigned short* xnH  = (unsigned short*)(ws + 12582912);
  unsigned short* xcH  = (unsigned short*)(ws + 17301504);
  unsigned short* yH   = (unsigned short*)(ws);
  unsigned short* WinF = (unsigned short*)(ws + 19398656);  //  65,536 u16
  unsigned short* WcatF = WinF + 65536;                     //  73,728 u16
  unsigned short* WoutF = WinF + 139264;                    //  32,768 u16

  k_prep<<<84, 256, 0, stream>>>(W_in, W_x, W_dt, W_out, WinF, WcatF, WoutF);
  k_ln  <<<dim3(kL / 64, kB), 256, 0, stream>>>(x, ln_w, ln_b, xnH);
  k_mfma<128, 512, 4, 0><<<dim3(kL / 64, 4, kB), 256, 0, stream>>>(xnH, WinF, nullptr, xiT, zT);
  k_conv<<<dim3(kL / 64, kE / 64, kB), 256, 0, stream>>>(xiT, conv_w, conv_b, xcT, xcH);
  k_mfma<256, 288, 2, 1><<<dim3(kL / 64, 2, kB), 256, 0, stream>>>(xcH, WcatF, b_dt, dtT, bcT);
  k_scanA<<<dim3(kNC, kE / 32, kB), 256, 0, stream>>>(dtT, xcT, bcT, A_log, hloc, aprod);
  k_prefix<<<kB * kE * kN / 256, 256, 0, stream>>>(hloc, aprod);
  k_scanC<<<dim3(kNC, kE / 32, kB), 256, 0, stream>>>(dtT, xcT, bcT, zT, A_log, Dp, hloc, yH);
  k_mfma<256, 128, 1, 2><<<dim3(kL / 64, 1, kB), 256, 0, stream>>>(yH, WoutF, nullptr, out, nullptr);
}

// Round 7
// 131.849 us; speedup vs baseline: 3.1624x; 1.1227x over previous
//
#include <hip/hip_runtime.h>

// Problem constants
constexpr int kB  = 2;
constexpr int kL  = 8192;   // d*h*w = 8*32*32
constexpr int kC  = 128;    // D_MODEL
constexpr int kE  = 256;    // D_INNER
constexpr int kN  = 16;     // D_STATE
constexpr int kCL = 64;     // scan chunk length
constexpr int kNC = kL / kCL; // 128 chunks per batch

typedef __attribute__((ext_vector_type(8))) short bf16x8;
typedef __attribute__((ext_vector_type(4))) float f32x4;
typedef __attribute__((ext_vector_type(8))) unsigned short u16x8;

__device__ __forceinline__ float silu(float v) { return v / (1.f + __expf(-v)); }
__device__ __forceinline__ float softplusf(float s) {
  return fmaxf(s, 0.f) + log1pf(__expf(-fabsf(s)));
}
__device__ __forceinline__ unsigned short f2bf(float x) {
  unsigned u = __float_as_uint(x);
  u += 0x7FFF + ((u >> 16) & 1);
  return (unsigned short)(u >> 16);
}
// Sum over aligned 8-lane groups entirely on the VALU pipe (DPP), no DS ops.
__device__ __forceinline__ float dpp_red8(float v) {
  v += __int_as_float(__builtin_amdgcn_mov_dpp(__float_as_int(v), 0xB1, 0xF, 0xF, true));
  v += __int_as_float(__builtin_amdgcn_mov_dpp(__float_as_int(v), 0x4E, 0xF, 0xF, true));
  v += __int_as_float(__builtin_amdgcn_mov_dpp(__float_as_int(v), 0x141, 0xF, 0xF, true));
  return v;
}

// ---------------------------------------------------------------------------
// Kernel: fused weight-prep (blocks 0..83) + LayerNorm (blocks 84..339).
// prep: bf16 A-frag blobs (verified m89/m97 layout).
// ln:   x [b][c][L] -> xnH bf16 token-major [b][l][128].
// ---------------------------------------------------------------------------
__global__ __launch_bounds__(256) void k_pre(const float* __restrict__ W_in,
                                             const float* __restrict__ W_x,
                                             const float* __restrict__ W_dt,
                                             const float* __restrict__ W_out,
                                             unsigned short* __restrict__ WinF,
                                             unsigned short* __restrict__ WcatF,
                                             unsigned short* __restrict__ WoutF,
                                             const float* __restrict__ x,
                                             const float* __restrict__ ln_w,
                                             const float* __restrict__ ln_b,
                                             unsigned short* __restrict__ xnH) {
  const int tid = threadIdx.x;
  if (blockIdx.x < 84) {
    const int f = blockIdx.x * 256 + tid;
    u16x8 o;
    if (f < 8192) {
      const int lane = f & 63, ks = (f >> 6) & 3, mt = f >> 8;
      const int m = mt * 16 + (lane & 15), kb = ks * 32 + ((lane >> 4) << 3);
      #pragma unroll
      for (int j = 0; j < 8; ++j) o[j] = f2bf(W_in[m * 128 + kb + j]);
      *(u16x8*)&WinF[(size_t)f * 8] = o;
    } else if (f < 17408) {
      const int g = f - 8192;
      const int lane = g & 63, ks = (g >> 6) & 7, mt = g >> 9;
      const int m = mt * 16 + (lane & 15), kb = ks * 32 + ((lane >> 4) << 3);
      if (m < 256) {
        #pragma unroll
        for (int j = 0; j < 8; ++j) {
          float s = 0.f;
          #pragma unroll
          for (int r = 0; r < 8; ++r) s = fmaf(W_dt[m * 8 + r], W_x[r * 256 + kb + j], s);
          o[j] = f2bf(s);
        }
      } else {
        #pragma unroll
        for (int j = 0; j < 8; ++j) o[j] = f2bf(W_x[(8 + m - 256) * 256 + kb + j]);
      }
      *(u16x8*)&WcatF[(size_t)g * 8] = o;
    } else {
      const int g = f - 17408;
      const int lane = g & 63, ks = (g >> 6) & 7, mt = g >> 9;
      const int m = mt * 16 + (lane & 15), kb = ks * 32 + ((lane >> 4) << 3);
      #pragma unroll
      for (int j = 0; j < 8; ++j) o[j] = f2bf(W_out[m * 256 + kb + j]);
      *(u16x8*)&WoutF[(size_t)g * 8] = o;
    }
    return;
  }
  // ---- LayerNorm part ----
  __shared__ float tile[64 * 132];
  __shared__ float smu[64], srs[64];
  const int bx2 = blockIdx.x - 84;
  const int b = bx2 >> 7, l0 = (bx2 & 127) * 64;
  const int cc = tid >> 6, lt = tid & 63;
  const float* xb = x + (size_t)b * kC * kL;
  for (int c0 = 0; c0 < kC; c0 += 4)
    tile[lt * 132 + c0 + cc] = xb[(size_t)(c0 + cc) * kL + l0 + lt];
  __syncthreads();
  const int l = tid >> 2, q = tid & 3;
  float s = 0.f, s2 = 0.f;
  #pragma unroll
  for (int i = 0; i < 32; ++i) {
    const float v = tile[l * 132 + q + 4 * i];
    s += v; s2 += v * v;
  }
  s += __shfl_xor(s, 1);  s2 += __shfl_xor(s2, 1);
  s += __shfl_xor(s, 2);  s2 += __shfl_xor(s2, 2);
  if (q == 0) {
    const float mu = s * (1.f / 128.f);
    const float var = s2 * (1.f / 128.f) - mu * mu;
    smu[l] = mu; srs[l] = rsqrtf(var + 1e-5f);
  }
  __syncthreads();
  #pragma unroll
  for (int it = 0; it < 4; ++it) {
    const int fidx = tid + it * 256;
    const int li = fidx >> 4, c8 = fidx & 15;
    const float4 v0 = *(const float4*)&tile[li * 132 + c8 * 8];
    const float4 v1 = *(const float4*)&tile[li * 132 + c8 * 8 + 4];
    const float4 w0 = *(const float4*)&ln_w[c8 * 8];
    const float4 w1 = *(const float4*)&ln_w[c8 * 8 + 4];
    const float4 b0 = *(const float4*)&ln_b[c8 * 8];
    const float4 b1 = *(const float4*)&ln_b[c8 * 8 + 4];
    const float mu = smu[li], rs = srs[li];
    u16x8 o;
    o[0] = f2bf((v0.x - mu) * rs * w0.x + b0.x);
    o[1] = f2bf((v0.y - mu) * rs * w0.y + b0.y);
    o[2] = f2bf((v0.z - mu) * rs * w0.z + b0.z);
    o[3] = f2bf((v0.w - mu) * rs * w0.w + b0.w);
    o[4] = f2bf((v1.x - mu) * rs * w1.x + b1.x);
    o[5] = f2bf((v1.y - mu) * rs * w1.y + b1.y);
    o[6] = f2bf((v1.z - mu) * rs * w1.z + b1.z);
    o[7] = f2bf((v1.w - mu) * rs * w1.w + b1.w);
    *(u16x8*)&xnH[((size_t)b * kL + l0 + li) * kC + c8 * 8] = o;
  }
}

// ---------------------------------------------------------------------------
// Unified MFMA GEMM (unchanged).
// ---------------------------------------------------------------------------
template<int K, int M, int CT, int VARIANT>
__global__ __launch_bounds__(256) void k_mfma(const unsigned short* __restrict__ XH,
                                              const unsigned short* __restrict__ WF,
                                              const float* __restrict__ bdt,
                                              float* __restrict__ out0,
                                              float* __restrict__ out1) {
  constexpr int KS = K / 32;
  constexpr int MT_BLK = M / 16 / CT;
  constexpr int MT_W = (MT_BLK + 3) / 4;
  constexpr int KPAD = K + 8;
  __shared__ unsigned short Xs[64 * KPAD];
  const int b = blockIdx.z, ct = blockIdx.y, l0 = blockIdx.x * 64;
  const int tid = threadIdx.x, lane = tid & 63, w = tid >> 6;
  for (int si = tid; si < 64 * K / 8; si += 256) {
    const int l = si / (K / 8), k8 = si % (K / 8);
    *(uint4*)&Xs[l * KPAD + k8 * 8] =
        *(const uint4*)&XH[((size_t)(b * kL + l0 + l)) * K + k8 * 8];
  }
  __syncthreads();
  f32x4 acc[MT_W][4];
  #pragma unroll
  for (int i = 0; i < MT_W; ++i)
    #pragma unroll
    for (int lt = 0; lt < 4; ++lt) acc[i][lt] = (f32x4){0.f, 0.f, 0.f, 0.f};
  const int colo = lane & 15, kgrp = (lane >> 4) * 8;
  for (int ks = 0; ks < KS; ++ks) {
    bf16x8 Bf[4];
    #pragma unroll
    for (int lt = 0; lt < 4; ++lt)
      Bf[lt] = *(const bf16x8*)&Xs[(lt * 16 + colo) * KPAD + ks * 32 + kgrp];
    #pragma unroll
    for (int i = 0; i < MT_W; ++i) {
      const int mt = w + 4 * i;
      if (mt < MT_BLK) {
        const int mt_g = ct * MT_BLK + mt;
        const bf16x8 Af = *(const bf16x8*)&WF[(size_t)((mt_g * KS + ks) * 64 + lane) * 8];
        #pragma unroll
        for (int lt = 0; lt < 4; ++lt)
          acc[i][lt] = __builtin_amdgcn_mfma_f32_16x16x32_bf16(Af, Bf[lt], acc[i][lt], 0, 0, 0);
      }
    }
  }
  #pragma unroll
  for (int i = 0; i < MT_W; ++i) {
    const int mt = w + 4 * i;
    if (mt >= MT_BLK) continue;
    const int mbase = (ct * MT_BLK + mt) * 16 + (lane >> 4) * 4;
    #pragma unroll
    for (int r = 0; r < 4; ++r) {
      const int m = mbase + r;
      #pragma unroll
      for (int lt = 0; lt < 4; ++lt) {
        const int lg = l0 + lt * 16 + colo;
        const float v = acc[i][lt][r];
        if (VARIANT == 0) {
          if (m < 256) out0[((size_t)b * kE + m) * kL + lg] = v;
          else         out1[((size_t)b * kE + m - 256) * kL + lg] = v;
        } else if (VARIANT == 1) {
          if (m < 256) out0[((size_t)b * kE + m) * kL + lg] = softplusf(v + bdt[m]);
          else         out1[((size_t)b * 32 + m - 256) * kL + lg] = v;
        } else {
          out0[((size_t)b * kC + m) * kL + lg] = v;
        }
      }
    }
  }
}

// ---------------------------------------------------------------------------
// Kernel: depthwise causal conv + silu, tiled 64e x 64l (unchanged).
// ---------------------------------------------------------------------------
__global__ __launch_bounds__(256) void k_conv(const float* __restrict__ xiT,
                                              const float* __restrict__ conv_w,
                                              const float* __restrict__ conv_b,
                                              float* __restrict__ xcT,
                                              unsigned short* __restrict__ xcH) {
  __shared__ unsigned short ht[64 * 72];   // [e][l] bf16, pad 72
  const int b = blockIdx.z, e0 = blockIdx.y * 64, l0 = blockIdx.x * 64;
  const int tid = threadIdx.x;
  const int e = tid >> 2, q = tid & 3;
  const int ge = e0 + e;
  const float4 cw = ((const float4*)conv_w)[ge];
  const float cb = conv_b[ge];
  const size_t base = ((size_t)b * kE + ge) * kL + l0 + q * 16;
  const float4* src = (const float4*)(xiT + base);
  float xb[20];
  if (l0 + q * 16) {
    const float4 p = src[-1];
    xb[0] = p.x; xb[1] = p.y; xb[2] = p.z; xb[3] = p.w;
  } else {
    xb[0] = xb[1] = xb[2] = xb[3] = 0.f;
  }
  #pragma unroll
  for (int m = 0; m < 4; ++m) {
    const float4 v = src[m];
    xb[4 + 4 * m] = v.x; xb[5 + 4 * m] = v.y; xb[6 + 4 * m] = v.z; xb[7 + 4 * m] = v.w;
  }
  float o[16];
  #pragma unroll
  for (int p = 0; p < 16; ++p) {
    float s = cb + cw.x * xb[p + 1] + cw.y * xb[p + 2] + cw.z * xb[p + 3] + cw.w * xb[p + 4];
    o[p] = silu(s);
  }
  float4* dst = (float4*)(xcT + base);
  #pragma unroll
  for (int m = 0; m < 4; ++m) {
    float4 ov; ov.x = o[4 * m]; ov.y = o[4 * m + 1]; ov.z = o[4 * m + 2]; ov.w = o[4 * m + 3];
    dst[m] = ov;
  }
  u16x8 h0, h1;
  #pragma unroll
  for (int i = 0; i < 8; ++i) { h0[i] = f2bf(o[i]); h1[i] = f2bf(o[8 + i]); }
  *(u16x8*)&ht[e * 72 + q * 16]     = h0;
  *(u16x8*)&ht[e * 72 + q * 16 + 8] = h1;
  __syncthreads();
  const int l = tid >> 2, g = tid & 3;
  u16x8 r0, r1;
  #pragma unroll
  for (int i = 0; i < 8; ++i) {
    r0[i] = ht[(g * 16 + i) * 72 + l];
    r1[i] = ht[(g * 16 + 8 + i) * 72 + l];
  }
  unsigned short* orow = &xcH[((size_t)b * kL + l0 + l) * kE + e0 + g * 16];
  *(u16x8*)orow = r0;
  *(u16x8*)(orow + 8) = r1;
}

// ---------------------------------------------------------------------------
// Kernel: scan phase A — b128-packed LDS, 2 DS reads per 2 l.
// ---------------------------------------------------------------------------
__global__ __launch_bounds__(256) void k_scanA(const float* __restrict__ dtT,
                                               const float* __restrict__ xcT,
                                               const float* __restrict__ bcT,
                                               const float* __restrict__ A_log,
                                               float* __restrict__ hloc,
                                               float* __restrict__ aprod) {
  __shared__ float dxi[32 * 132];
  __shared__ float Bp[8 * 132];
  const int b = blockIdx.z, ch = blockIdx.x, d0 = blockIdx.y * 32;
  const int l0 = ch * kCL, tid = threadIdx.x;
  {
    const int ds = tid >> 3, ng = tid & 7;
    const float4* dsrc = (const float4*)&dtT[((size_t)b * kE + d0 + ds) * kL + l0 + 8 * ng];
    const float4* xsrc = (const float4*)&xcT[((size_t)b * kE + d0 + ds) * kL + l0 + 8 * ng];
    float* wr = &dxi[ds * 132 + 16 * ng];
    #pragma unroll
    for (int m = 0; m < 2; ++m) {
      const float4 dv = dsrc[m], xv = xsrc[m];
      *(float4*)&wr[8 * m]     = make_float4(dv.x, dv.x * xv.x, dv.y, dv.y * xv.y);
      *(float4*)&wr[8 * m + 4] = make_float4(dv.z, dv.z * xv.z, dv.w, dv.w * xv.w);
    }
  }
  if (tid < 128) {
    const int ng = tid & 7, lq = tid >> 3;     // lq 0..15
    const float4 b0 = *(const float4*)&bcT[((size_t)b * 32 + 2 * ng) * kL + l0 + 4 * lq];
    const float4 b1 = *(const float4*)&bcT[((size_t)b * 32 + 2 * ng + 1) * kL + l0 + 4 * lq];
    float* wr = &Bp[ng * 132 + 8 * lq];
    *(float4*)&wr[0] = make_float4(b0.x, b1.x, b0.y, b1.y);
    *(float4*)&wr[4] = make_float4(b0.z, b1.z, b0.w, b1.w);
  }
  __syncthreads();
  const int ds = tid >> 3, ng = tid & 7;
  const int d = d0 + ds;
  const float2 Al = *(const float2*)&A_log[d * kN + 2 * ng];
  const float Av0 = -__expf(Al.x), Av1 = -__expf(Al.y);
  float h0 = 0.f, h1 = 0.f, sdt = 0.f;
  const float* drow = &dxi[ds * 132];
  const float* brow = &Bp[ng * 132];
  #pragma unroll 4
  for (int l = 0; l < kCL; l += 2) {
    const float4 du = *(const float4*)&drow[2 * l];   // dt,u @ l ; dt,u @ l+1
    const float4 bb = *(const float4*)&brow[2 * l];   // B0,B1 @ l ; B0,B1 @ l+1
    sdt += du.x + du.z;
    h0 = fmaf(__expf(Av0 * du.x), h0, bb.x * du.y);
    h1 = fmaf(__expf(Av1 * du.x), h1, bb.y * du.y);
    h0 = fmaf(__expf(Av0 * du.z), h0, bb.z * du.w);
    h1 = fmaf(__expf(Av1 * du.z), h1, bb.w * du.w);
  }
  const size_t base = (((size_t)b * kNC + ch) * kE + d) * kN + 2 * ng;
  *(float2*)&hloc[base] = make_float2(h0, h1);
  *(float2*)&aprod[base] = make_float2(__expf(Av0 * sdt), __expf(Av1 * sdt));
}

// ---------------------------------------------------------------------------
// Kernel: sequential prefix over chunks, IN-PLACE (hs: hloc in, hinit out)
// ---------------------------------------------------------------------------
__global__ __launch_bounds__(256) void k_prefix(float* __restrict__ hs,
                                                const float* __restrict__ aprod) {
  const int t = blockIdx.x * 256 + threadIdx.x;  // 8192 = B*E*N
  const int b = t >> 12, dn = t & 4095;
  float h = 0.f;
  #pragma unroll 8
  for (int c = 0; c < kNC; ++c) {
    const size_t idx = ((size_t)b * kNC + c) * 4096 + dn;
    const float hl = hs[idx];
    const float ap = aprod[idx];
    hs[idx] = h;
    h = fmaf(ap, h, hl);
  }
}

// ---------------------------------------------------------------------------
// Kernel: scan phase C — register-y (full unroll), 3 DS ops per 2 l,
// yt aliased over dxi (dead after loop). DPP y-reduce on VALU pipe.
// ---------------------------------------------------------------------------
__global__ __launch_bounds__(256) void k_scanC(const float* __restrict__ dtT,
                                               const float* __restrict__ xcT,
                                               const float* __restrict__ bcT,
                                               const float* __restrict__ zT,
                                               const float* __restrict__ A_log,
                                               const float* __restrict__ Dp,
                                               const float* __restrict__ hinit,
                                               unsigned short* __restrict__ yH) {
  __shared__ float dxi[32 * 132];      // staging; aliased by yt[32*72] post-loop
  __shared__ float bc4[8 * 260];
  float* yt = dxi;
  const int b = blockIdx.z, ch = blockIdx.x, d0 = blockIdx.y * 32;
  const int l0 = ch * kCL, tid = threadIdx.x;
  {
    const int ds = tid >> 3, ng = tid & 7;
    const float4* dsrc = (const float4*)&dtT[((size_t)b * kE + d0 + ds) * kL + l0 + 8 * ng];
    const float4* xsrc = (const float4*)&xcT[((size_t)b * kE + d0 + ds) * kL + l0 + 8 * ng];
    float* wr = &dxi[ds * 132 + 16 * ng];
    #pragma unroll
    for (int m = 0; m < 2; ++m) {
      const float4 dv = dsrc[m], xv = xsrc[m];
      *(float4*)&wr[8 * m]     = make_float4(dv.x, dv.x * xv.x, dv.y, dv.y * xv.y);
      *(float4*)&wr[8 * m + 4] = make_float4(dv.z, dv.z * xv.z, dv.w, dv.w * xv.w);
    }
  }
  if (tid < 128) {
    const int ng = tid & 7, lq = tid >> 3;     // lq 0..15
    const float4 b0 = *(const float4*)&bcT[((size_t)b * 32 + 2 * ng) * kL + l0 + 4 * lq];
    const float4 c0 = *(const float4*)&bcT[((size_t)b * 32 + 16 + 2 * ng) * kL + l0 + 4 * lq];
    const float4 b1 = *(const float4*)&bcT[((size_t)b * 32 + 2 * ng + 1) * kL + l0 + 4 * lq];
    const float4 c1 = *(const float4*)&bcT[((size_t)b * 32 + 17 + 2 * ng) * kL + l0 + 4 * lq];
    float* wr = &bc4[ng * 260 + 16 * lq];
    *(float4*)&wr[0]  = make_float4(b0.x, c0.x, b1.x, c1.x);
    *(float4*)&wr[4]  = make_float4(b0.y, c0.y, b1.y, c1.y);
    *(float4*)&wr[8]  = make_float4(b0.z, c0.z, b1.z, c1.z);
    *(float4*)&wr[12] = make_float4(b0.w, c0.w, b1.w, c1.w);
  }
  __syncthreads();
  const int ds = tid >> 3, ng = tid & 7;
  const int d = d0 + ds;
  const float2 Al = *(const float2*)&A_log[d * kN + 2 * ng];
  const float Av0 = -__expf(Al.x), Av1 = -__expf(Al.y);
  const size_t hbase = (((size_t)b * kNC + ch) * kE + d) * kN + 2 * ng;
  const float2 hv = *(const float2*)&hinit[hbase];
  float h0 = hv.x, h1 = hv.y;
  const float* drow = &dxi[ds * 132];
  const float* brow = &bc4[ng * 260];
  float yreg[8];
  #pragma unroll
  for (int l = 0; l < kCL; l += 2) {
    const float4 du  = *(const float4*)&drow[2 * l];      // dt,u @ l ; dt,u @ l+1
    const float4 bcA = *(const float4*)&brow[4 * l];      // B0,C0,B1,C1 @ l
    const float4 bcB = *(const float4*)&brow[4 * l + 4];  // @ l+1
    h0 = fmaf(__expf(Av0 * du.x), h0, bcA.x * du.y);
    h1 = fmaf(__expf(Av1 * du.x), h1, bcA.z * du.y);
    const float ylo = dpp_red8(fmaf(h0, bcA.y, h1 * bcA.w));
    h0 = fmaf(__expf(Av0 * du.z), h0, bcB.x * du.w);
    h1 = fmaf(__expf(Av1 * du.z), h1, bcB.z * du.w);
    const float yhi = dpp_red8(fmaf(h0, bcB.y, h1 * bcB.w));
    // lane (ng == l&7) owns y[l]; static index l>>3 under full unroll
    if (ng == (l & 7))       yreg[l >> 3] = ylo;
    if (ng == ((l + 1) & 7)) yreg[l >> 3] = yhi;
  }
  __syncthreads();           // all waves done reading dxi — safe to alias as yt
  #pragma unroll
  for (int k = 0; k < 8; ++k)
    yt[ds * 72 + 8 * k + ng] = yreg[k];
  __syncthreads();
  // epilogue: gating, coalesced token-major u16x8 stores (xc/z from global)
  const int l = tid >> 2, g = tid & 3;
  u16x8 ov;
  #pragma unroll
  for (int i = 0; i < 8; ++i) {
    const int dd = g * 8 + i;
    const float yv = yt[dd * 72 + l];
    const float xv = xcT[((size_t)b * kE + d0 + dd) * kL + l0 + l];
    const float zv = zT[((size_t)b * kE + d0 + dd) * kL + l0 + l];
    const float o = fmaf(xv, Dp[d0 + dd], yv) * silu(zv);
    ov[i] = f2bf(o);
  }
  *(u16x8*)&yH[((size_t)b * kL + l0 + l) * kE + d0 + g * 8] = ov;
}

// ---------------------------------------------------------------------------
extern "C" void kernel_launch(void* const* d_in, const int* in_sizes, int n_in,
                              void* d_out, int out_size, void* d_ws, size_t ws_size,
                              hipStream_t stream) {
  (void)in_sizes; (void)n_in; (void)out_size; (void)ws_size;
  const float* x      = (const float*)d_in[0];
  const float* ln_w   = (const float*)d_in[1];
  const float* ln_b   = (const float*)d_in[2];
  const float* W_in   = (const float*)d_in[3];
  const float* conv_w = (const float*)d_in[4];
  const float* conv_b = (const float*)d_in[5];
  const float* W_x    = (const float*)d_in[6];
  const float* W_dt   = (const float*)d_in[7];
  const float* b_dt   = (const float*)d_in[8];
  const float* A_log  = (const float*)d_in[9];
  const float* Dp     = (const float*)d_in[10];
  const float* W_out  = (const float*)d_in[11];
  float* out = (float*)d_out;
  float* ws  = (float*)d_ws;

  // workspace layout (float offsets), ~77.9 MB
  float* xiT   = ws;                    // 4,194,304 fp32 [b][256][L]; later aliased by yH
  float* zT    = ws + 4194304;          // 4,194,304
  float* xcT   = ws + 8388608;          // 4,194,304
  float* dtT   = ws + 12582912;         // 4,194,304; alias: xnH bf16 (dead before dbc)
  float* bcT   = ws + 16777216;         //   524,288 [b][32][L]
  float* hloc  = ws + 17301504;         // 1,048,576 (aliases xcH; xcH dead after dbc)
  float* aprod = ws + 18350080;         // 1,048,576
  unsigned short* xnH  = (unsigned short*)(ws + 12582912);
  unsigned short* xcH  = (unsigned short*)(ws + 17301504);
  unsigned short* yH   = (unsigned short*)(ws);
  unsigned short* WinF = (unsigned short*)(ws + 19398656);  //  65,536 u16
  unsigned short* WcatF = WinF + 65536;                     //  73,728 u16
  unsigned short* WoutF = WinF + 139264;                    //  32,768 u16

  k_pre <<<340, 256, 0, stream>>>(W_in, W_x, W_dt, W_out, WinF, WcatF, WoutF,
                                  x, ln_w, ln_b, xnH);
  k_mfma<128, 512, 4, 0><<<dim3(kL / 64, 4, kB), 256, 0, stream>>>(xnH, WinF, nullptr, xiT, zT);
  k_conv<<<dim3(kL / 64, kE / 64, kB), 256, 0, stream>>>(xiT, conv_w, conv_b, xcT, xcH);
  k_mfma<256, 288, 2, 1><<<dim3(kL / 64, 2, kB), 256, 0, stream>>>(xcH, WcatF, b_dt, dtT, bcT);
  k_scanA<<<dim3(kNC, kE / 32, kB), 256, 0, stream>>>(dtT, xcT, bcT, A_log, hloc, aprod);
  k_prefix<<<kB * kE * kN / 256, 256, 0, stream>>>(hloc, aprod);
  k_scanC<<<dim3(kNC, kE / 32, kB), 256, 0, stream>>>(dtT, xcT, bcT, zT, A_log, Dp, hloc, yH);
  k_mfma<256, 128, 1, 2><<<dim3(kL / 64, 1, kB), 256, 0, stream>>>(yH, WoutF, nullptr, out, nullptr);
}

// Round 8
// 118.301 us; speedup vs baseline: 3.5246x; 1.1145x over previous
//
#include <hip/hip_runtime.h>

// Problem constants
constexpr int kB  = 2;
constexpr int kL  = 8192;   // d*h*w = 8*32*32
constexpr int kC  = 128;    // D_MODEL
constexpr int kE  = 256;    // D_INNER
constexpr int kN  = 16;     // D_STATE
constexpr int kCL = 64;     // scan chunk length
constexpr int kNC = kL / kCL; // 128 chunks per batch

typedef __attribute__((ext_vector_type(8))) short bf16x8;
typedef __attribute__((ext_vector_type(4))) float f32x4;
typedef __attribute__((ext_vector_type(8))) unsigned short u16x8;

__device__ __forceinline__ float silu(float v) { return v / (1.f + __expf(-v)); }
__device__ __forceinline__ float softplusf(float s) {
  return fmaxf(s, 0.f) + log1pf(__expf(-fabsf(s)));
}
__device__ __forceinline__ unsigned short f2bf(float x) {
  unsigned u = __float_as_uint(x);
  u += 0x7FFF + ((u >> 16) & 1);
  return (unsigned short)(u >> 16);
}
__device__ __forceinline__ float bf2f(unsigned short x) {
  return __uint_as_float(((unsigned)x) << 16);
}
// Sum over aligned 8-lane groups entirely on the VALU pipe (DPP), no DS ops.
__device__ __forceinline__ float dpp_red8(float v) {
  v += __int_as_float(__builtin_amdgcn_mov_dpp(__float_as_int(v), 0xB1, 0xF, 0xF, true));
  v += __int_as_float(__builtin_amdgcn_mov_dpp(__float_as_int(v), 0x4E, 0xF, 0xF, true));
  v += __int_as_float(__builtin_amdgcn_mov_dpp(__float_as_int(v), 0x141, 0xF, 0xF, true));
  return v;
}

// ---------------------------------------------------------------------------
// Kernel: fused weight-prep (blocks 0..83) + LayerNorm (blocks 84..339).
// ---------------------------------------------------------------------------
__global__ __launch_bounds__(256) void k_pre(const float* __restrict__ W_in,
                                             const float* __restrict__ W_x,
                                             const float* __restrict__ W_dt,
                                             const float* __restrict__ W_out,
                                             unsigned short* __restrict__ WinF,
                                             unsigned short* __restrict__ WcatF,
                                             unsigned short* __restrict__ WoutF,
                                             const float* __restrict__ x,
                                             const float* __restrict__ ln_w,
                                             const float* __restrict__ ln_b,
                                             unsigned short* __restrict__ xnH) {
  const int tid = threadIdx.x;
  if (blockIdx.x < 84) {
    const int f = blockIdx.x * 256 + tid;
    u16x8 o;
    if (f < 8192) {
      const int lane = f & 63, ks = (f >> 6) & 3, mt = f >> 8;
      const int m = mt * 16 + (lane & 15), kb = ks * 32 + ((lane >> 4) << 3);
      #pragma unroll
      for (int j = 0; j < 8; ++j) o[j] = f2bf(W_in[m * 128 + kb + j]);
      *(u16x8*)&WinF[(size_t)f * 8] = o;
    } else if (f < 17408) {
      const int g = f - 8192;
      const int lane = g & 63, ks = (g >> 6) & 7, mt = g >> 9;
      const int m = mt * 16 + (lane & 15), kb = ks * 32 + ((lane >> 4) << 3);
      if (m < 256) {
        #pragma unroll
        for (int j = 0; j < 8; ++j) {
          float s = 0.f;
          #pragma unroll
          for (int r = 0; r < 8; ++r) s = fmaf(W_dt[m * 8 + r], W_x[r * 256 + kb + j], s);
          o[j] = f2bf(s);
        }
      } else {
        #pragma unroll
        for (int j = 0; j < 8; ++j) o[j] = f2bf(W_x[(8 + m - 256) * 256 + kb + j]);
      }
      *(u16x8*)&WcatF[(size_t)g * 8] = o;
    } else {
      const int g = f - 17408;
      const int lane = g & 63, ks = (g >> 6) & 7, mt = g >> 9;
      const int m = mt * 16 + (lane & 15), kb = ks * 32 + ((lane >> 4) << 3);
      #pragma unroll
      for (int j = 0; j < 8; ++j) o[j] = f2bf(W_out[m * 256 + kb + j]);
      *(u16x8*)&WoutF[(size_t)g * 8] = o;
    }
    return;
  }
  // ---- LayerNorm part ----
  __shared__ float tile[64 * 132];
  __shared__ float smu[64], srs[64];
  const int bx2 = blockIdx.x - 84;
  const int b = bx2 >> 7, l0 = (bx2 & 127) * 64;
  const int cc = tid >> 6, lt = tid & 63;
  const float* xb = x + (size_t)b * kC * kL;
  for (int c0 = 0; c0 < kC; c0 += 4)
    tile[lt * 132 + c0 + cc] = xb[(size_t)(c0 + cc) * kL + l0 + lt];
  __syncthreads();
  const int l = tid >> 2, q = tid & 3;
  float s = 0.f, s2 = 0.f;
  #pragma unroll
  for (int i = 0; i < 32; ++i) {
    const float v = tile[l * 132 + q + 4 * i];
    s += v; s2 += v * v;
  }
  s += __shfl_xor(s, 1);  s2 += __shfl_xor(s2, 1);
  s += __shfl_xor(s, 2);  s2 += __shfl_xor(s2, 2);
  if (q == 0) {
    const float mu = s * (1.f / 128.f);
    const float var = s2 * (1.f / 128.f) - mu * mu;
    smu[l] = mu; srs[l] = rsqrtf(var + 1e-5f);
  }
  __syncthreads();
  #pragma unroll
  for (int it = 0; it < 4; ++it) {
    const int fidx = tid + it * 256;
    const int li = fidx >> 4, c8 = fidx & 15;
    const float4 v0 = *(const float4*)&tile[li * 132 + c8 * 8];
    const float4 v1 = *(const float4*)&tile[li * 132 + c8 * 8 + 4];
    const float4 w0 = *(const float4*)&ln_w[c8 * 8];
    const float4 w1 = *(const float4*)&ln_w[c8 * 8 + 4];
    const float4 b0 = *(const float4*)&ln_b[c8 * 8];
    const float4 b1 = *(const float4*)&ln_b[c8 * 8 + 4];
    const float mu = smu[li], rs = srs[li];
    u16x8 o;
    o[0] = f2bf((v0.x - mu) * rs * w0.x + b0.x);
    o[1] = f2bf((v0.y - mu) * rs * w0.y + b0.y);
    o[2] = f2bf((v0.z - mu) * rs * w0.z + b0.z);
    o[3] = f2bf((v0.w - mu) * rs * w0.w + b0.w);
    o[4] = f2bf((v1.x - mu) * rs * w1.x + b1.x);
    o[5] = f2bf((v1.y - mu) * rs * w1.y + b1.y);
    o[6] = f2bf((v1.z - mu) * rs * w1.z + b1.z);
    o[7] = f2bf((v1.w - mu) * rs * w1.w + b1.w);
    *(u16x8*)&xnH[((size_t)b * kL + l0 + li) * kC + c8 * 8] = o;
  }
}

// ---------------------------------------------------------------------------
// Kernel: fused GEMM1 + depthwise conv + silu.
// ct 0..1: xi slices -> conv in-block -> xcT fp32 + xcH bf16 (no xiT buffer!)
// ct 2..3: z slices -> zT fp32.
// Boundary tokens l0-3..l0-1 recomputed via VALU dot (W_in fp32 x xnH).
// ---------------------------------------------------------------------------
__global__ __launch_bounds__(256) void k_g1conv(const unsigned short* __restrict__ xnH,
                                                const unsigned short* __restrict__ WF,
                                                const float* __restrict__ W_in,
                                                const float* __restrict__ conv_w,
                                                const float* __restrict__ conv_b,
                                                float* __restrict__ zT,
                                                float* __restrict__ xcT,
                                                unsigned short* __restrict__ xcH) {
  constexpr int KPAD = 136;
  __shared__ unsigned short Xs[64 * KPAD];   // staging; aliased as ht[64*72] later
  __shared__ float xi[128 * 69];             // conv input tile [m][3+64+pad]
  const int b = blockIdx.z, ct = blockIdx.y, l0 = blockIdx.x * 64;
  const int tid = threadIdx.x, lane = tid & 63, w = tid >> 6;
  for (int si = tid; si < 1024; si += 256) {
    const int l = si >> 4, k8 = si & 15;
    *(uint4*)&Xs[l * KPAD + k8 * 8] =
        *(const uint4*)&xnH[((size_t)(b * kL + l0 + l)) * kC + k8 * 8];
  }
  __syncthreads();
  // boundary-token xi via VALU (xi slices only); zeros when l0 == 0
  float s0 = 0.f, s1 = 0.f, s2 = 0.f;
  if (ct < 2 && tid < 128 && l0 > 0) {
    const int ge = ct * 128 + tid;
    const float4* wv = (const float4*)&W_in[ge * kC];
    const u16x8* x0 = (const u16x8*)&xnH[((size_t)b * kL + l0 - 3) * kC];
    const u16x8* x1 = (const u16x8*)&xnH[((size_t)b * kL + l0 - 2) * kC];
    const u16x8* x2 = (const u16x8*)&xnH[((size_t)b * kL + l0 - 1) * kC];
    #pragma unroll 4
    for (int k8 = 0; k8 < 16; ++k8) {
      const float4 wa = wv[2 * k8], wb = wv[2 * k8 + 1];
      const u16x8 a0 = x0[k8], a1 = x1[k8], a2 = x2[k8];
      const float wreg[8] = {wa.x, wa.y, wa.z, wa.w, wb.x, wb.y, wb.z, wb.w};
      #pragma unroll
      for (int j = 0; j < 8; ++j) {
        s0 = fmaf(wreg[j], bf2f(a0[j]), s0);
        s1 = fmaf(wreg[j], bf2f(a1[j]), s1);
        s2 = fmaf(wreg[j], bf2f(a2[j]), s2);
      }
    }
  }
  if (ct < 2 && tid < 128) {
    xi[tid * 69 + 0] = s0; xi[tid * 69 + 1] = s1; xi[tid * 69 + 2] = s2;
  }
  // MFMA: 128 rows of this ct-slice; waves do mt = w, w+4
  f32x4 acc[2][4];
  #pragma unroll
  for (int i = 0; i < 2; ++i)
    #pragma unroll
    for (int lt = 0; lt < 4; ++lt) acc[i][lt] = (f32x4){0.f, 0.f, 0.f, 0.f};
  const int colo = lane & 15, kgrp = (lane >> 4) * 8;
  for (int ks = 0; ks < 4; ++ks) {
    bf16x8 Bf[4];
    #pragma unroll
    for (int lt = 0; lt < 4; ++lt)
      Bf[lt] = *(const bf16x8*)&Xs[(lt * 16 + colo) * KPAD + ks * 32 + kgrp];
    #pragma unroll
    for (int i = 0; i < 2; ++i) {
      const int mt_g = ct * 8 + w + 4 * i;
      const bf16x8 Af = *(const bf16x8*)&WF[(size_t)((mt_g * 4 + ks) * 64 + lane) * 8];
      #pragma unroll
      for (int lt = 0; lt < 4; ++lt)
        acc[i][lt] = __builtin_amdgcn_mfma_f32_16x16x32_bf16(Af, Bf[lt], acc[i][lt], 0, 0, 0);
    }
  }
  if (ct >= 2) {   // z slices: direct store, done (uniform branch per block)
    #pragma unroll
    for (int i = 0; i < 2; ++i) {
      const int m = (ct * 8 + w + 4 * i) * 16 + (lane >> 4) * 4;   // 256..511
      #pragma unroll
      for (int r = 0; r < 4; ++r)
        #pragma unroll
        for (int lt = 0; lt < 4; ++lt)
          zT[((size_t)b * kE + m + r - 256) * kL + l0 + lt * 16 + colo] = acc[i][lt][r];
    }
    return;
  }
  // xi slices: acc -> LDS
  #pragma unroll
  for (int i = 0; i < 2; ++i) {
    const int mloc = (w + 4 * i) * 16 + (lane >> 4) * 4;
    #pragma unroll
    for (int r = 0; r < 4; ++r)
      #pragma unroll
      for (int lt = 0; lt < 4; ++lt)
        xi[(mloc + r) * 69 + 3 + lt * 16 + colo] = acc[i][lt][r];
  }
  __syncthreads();
  unsigned short* ht = Xs;   // Xs dead after MFMA loop; 64*72 u16 fits
  const int e = tid >> 2, q = tid & 3;
  #pragma unroll
  for (int half = 0; half < 2; ++half) {
    const int ee = e + 64 * half;
    const int ge = ct * 128 + ee;
    const float4 cw = ((const float4*)conv_w)[ge];
    const float cb = conv_b[ge];
    const float* xr = &xi[ee * 69 + q * 16];
    float o[16];
    #pragma unroll
    for (int j = 0; j < 16; ++j) {
      const float s = cb + cw.x * xr[j] + cw.y * xr[j + 1] + cw.z * xr[j + 2] + cw.w * xr[j + 3];
      o[j] = silu(s);
    }
    float4* dst = (float4*)&xcT[((size_t)b * kE + ge) * kL + l0 + q * 16];
    #pragma unroll
    for (int m = 0; m < 4; ++m) {
      float4 ov; ov.x = o[4 * m]; ov.y = o[4 * m + 1]; ov.z = o[4 * m + 2]; ov.w = o[4 * m + 3];
      dst[m] = ov;
    }
    u16x8 h0, h1;
    #pragma unroll
    for (int i = 0; i < 8; ++i) { h0[i] = f2bf(o[i]); h1[i] = f2bf(o[8 + i]); }
    if (half) __syncthreads();    // previous transpose reads done before overwrite
    *(u16x8*)&ht[e * 72 + q * 16]     = h0;
    *(u16x8*)&ht[e * 72 + q * 16 + 8] = h1;
    __syncthreads();
    const int lr = tid >> 2, g = tid & 3;
    u16x8 r0, r1;
    #pragma unroll
    for (int i = 0; i < 8; ++i) {
      r0[i] = ht[(g * 16 + i) * 72 + lr];
      r1[i] = ht[(g * 16 + 8 + i) * 72 + lr];
    }
    unsigned short* orow = &xcH[((size_t)b * kL + l0 + lr) * kE + ct * 128 + half * 64 + g * 16];
    *(u16x8*)orow = r0;
    *(u16x8*)(orow + 8) = r1;
  }
}

// ---------------------------------------------------------------------------
// Unified MFMA GEMM (VARIANT 1: dbc, VARIANT 2: gemm3) — unchanged.
// ---------------------------------------------------------------------------
template<int K, int M, int CT, int VARIANT>
__global__ __launch_bounds__(256) void k_mfma(const unsigned short* __restrict__ XH,
                                              const unsigned short* __restrict__ WF,
                                              const float* __restrict__ bdt,
                                              float* __restrict__ out0,
                                              float* __restrict__ out1) {
  constexpr int KS = K / 32;
  constexpr int MT_BLK = M / 16 / CT;
  constexpr int MT_W = (MT_BLK + 3) / 4;
  constexpr int KPAD = K + 8;
  __shared__ unsigned short Xs[64 * KPAD];
  const int b = blockIdx.z, ct = blockIdx.y, l0 = blockIdx.x * 64;
  const int tid = threadIdx.x, lane = tid & 63, w = tid >> 6;
  for (int si = tid; si < 64 * K / 8; si += 256) {
    const int l = si / (K / 8), k8 = si % (K / 8);
    *(uint4*)&Xs[l * KPAD + k8 * 8] =
        *(const uint4*)&XH[((size_t)(b * kL + l0 + l)) * K + k8 * 8];
  }
  __syncthreads();
  f32x4 acc[MT_W][4];
  #pragma unroll
  for (int i = 0; i < MT_W; ++i)
    #pragma unroll
    for (int lt = 0; lt < 4; ++lt) acc[i][lt] = (f32x4){0.f, 0.f, 0.f, 0.f};
  const int colo = lane & 15, kgrp = (lane >> 4) * 8;
  for (int ks = 0; ks < KS; ++ks) {
    bf16x8 Bf[4];
    #pragma unroll
    for (int lt = 0; lt < 4; ++lt)
      Bf[lt] = *(const bf16x8*)&Xs[(lt * 16 + colo) * KPAD + ks * 32 + kgrp];
    #pragma unroll
    for (int i = 0; i < MT_W; ++i) {
      const int mt = w + 4 * i;
      if (mt < MT_BLK) {
        const int mt_g = ct * MT_BLK + mt;
        const bf16x8 Af = *(const bf16x8*)&WF[(size_t)((mt_g * KS + ks) * 64 + lane) * 8];
        #pragma unroll
        for (int lt = 0; lt < 4; ++lt)
          acc[i][lt] = __builtin_amdgcn_mfma_f32_16x16x32_bf16(Af, Bf[lt], acc[i][lt], 0, 0, 0);
      }
    }
  }
  #pragma unroll
  for (int i = 0; i < MT_W; ++i) {
    const int mt = w + 4 * i;
    if (mt >= MT_BLK) continue;
    const int mbase = (ct * MT_BLK + mt) * 16 + (lane >> 4) * 4;
    #pragma unroll
    for (int r = 0; r < 4; ++r) {
      const int m = mbase + r;
      #pragma unroll
      for (int lt = 0; lt < 4; ++lt) {
        const int lg = l0 + lt * 16 + colo;
        const float v = acc[i][lt][r];
        if (VARIANT == 1) {
          if (m < 256) out0[((size_t)b * kE + m) * kL + lg] = softplusf(v + bdt[m]);
          else         out1[((size_t)b * 32 + m - 256) * kL + lg] = v;
        } else {
          out0[((size_t)b * kC + m) * kL + lg] = v;
        }
      }
    }
  }
}

// ---------------------------------------------------------------------------
// Kernel: scan phase A — b128-packed LDS, 2 DS reads per 2 l.
// ---------------------------------------------------------------------------
__global__ __launch_bounds__(256) void k_scanA(const float* __restrict__ dtT,
                                               const float* __restrict__ xcT,
                                               const float* __restrict__ bcT,
                                               const float* __restrict__ A_log,
                                               float* __restrict__ hloc,
                                               float* __restrict__ aprod) {
  __shared__ float dxi[32 * 132];
  __shared__ float Bp[8 * 132];
  const int b = blockIdx.z, ch = blockIdx.x, d0 = blockIdx.y * 32;
  const int l0 = ch * kCL, tid = threadIdx.x;
  {
    const int ds = tid >> 3, ng = tid & 7;
    const float4* dsrc = (const float4*)&dtT[((size_t)b * kE + d0 + ds) * kL + l0 + 8 * ng];
    const float4* xsrc = (const float4*)&xcT[((size_t)b * kE + d0 + ds) * kL + l0 + 8 * ng];
    float* wr = &dxi[ds * 132 + 16 * ng];
    #pragma unroll
    for (int m = 0; m < 2; ++m) {
      const float4 dv = dsrc[m], xv = xsrc[m];
      *(float4*)&wr[8 * m]     = make_float4(dv.x, dv.x * xv.x, dv.y, dv.y * xv.y);
      *(float4*)&wr[8 * m + 4] = make_float4(dv.z, dv.z * xv.z, dv.w, dv.w * xv.w);
    }
  }
  if (tid < 128) {
    const int ng = tid & 7, lq = tid >> 3;     // lq 0..15
    const float4 b0 = *(const float4*)&bcT[((size_t)b * 32 + 2 * ng) * kL + l0 + 4 * lq];
    const float4 b1 = *(const float4*)&bcT[((size_t)b * 32 + 2 * ng + 1) * kL + l0 + 4 * lq];
    float* wr = &Bp[ng * 132 + 8 * lq];
    *(float4*)&wr[0] = make_float4(b0.x, b1.x, b0.y, b1.y);
    *(float4*)&wr[4] = make_float4(b0.z, b1.z, b0.w, b1.w);
  }
  __syncthreads();
  const int ds = tid >> 3, ng = tid & 7;
  const int d = d0 + ds;
  const float2 Al = *(const float2*)&A_log[d * kN + 2 * ng];
  const float Av0 = -__expf(Al.x), Av1 = -__expf(Al.y);
  float h0 = 0.f, h1 = 0.f, sdt = 0.f;
  const float* drow = &dxi[ds * 132];
  const float* brow = &Bp[ng * 132];
  #pragma unroll 4
  for (int l = 0; l < kCL; l += 2) {
    const float4 du = *(const float4*)&drow[2 * l];
    const float4 bb = *(const float4*)&brow[2 * l];
    sdt += du.x + du.z;
    h0 = fmaf(__expf(Av0 * du.x), h0, bb.x * du.y);
    h1 = fmaf(__expf(Av1 * du.x), h1, bb.y * du.y);
    h0 = fmaf(__expf(Av0 * du.z), h0, bb.z * du.w);
    h1 = fmaf(__expf(Av1 * du.z), h1, bb.w * du.w);
  }
  const size_t base = (((size_t)b * kNC + ch) * kE + d) * kN + 2 * ng;
  *(float2*)&hloc[base] = make_float2(h0, h1);
  *(float2*)&aprod[base] = make_float2(__expf(Av0 * sdt), __expf(Av1 * sdt));
}

// ---------------------------------------------------------------------------
// Kernel: prefix over chunks, 8 segment-threads per (b,d,n) row.
// In-place (hs: hloc in, hinit out). 65536 threads = 256 blocks.
// ---------------------------------------------------------------------------
__global__ __launch_bounds__(256) void k_prefix8(float* __restrict__ hs,
                                                 const float* __restrict__ aprod) {
  const int t = blockIdx.x * 256 + threadIdx.x;
  const int row = t >> 3, seg = t & 7;           // row = b*4096 + dn
  const int b = row >> 12, dn = row & 4095;
  const size_t idx0 = ((size_t)b * kNC + seg * 16) * 4096 + dn;
  float hl[16], ap[16];
  #pragma unroll
  for (int i = 0; i < 16; ++i) {
    hl[i] = hs[idx0 + (size_t)i * 4096];
    ap[i] = aprod[idx0 + (size_t)i * 4096];
  }
  float H = 0.f, A = 1.f;
  #pragma unroll
  for (int i = 0; i < 16; ++i) { H = fmaf(ap[i], H, hl[i]); A *= ap[i]; }
  // inclusive scan over the 8 aligned segment-lanes
  #pragma unroll
  for (int off = 1; off < 8; off <<= 1) {
    const float Ho = __shfl_up(H, off, 8);
    const float Ao = __shfl_up(A, off, 8);
    if (seg >= off) { H = fmaf(A, Ho, H); A *= Ao; }
  }
  const float Hprev = __shfl_up(H, 1, 8);
  float h = (seg == 0) ? 0.f : Hprev;
  #pragma unroll
  for (int i = 0; i < 16; ++i) {
    hs[idx0 + (size_t)i * 4096] = h;
    h = fmaf(ap[i], h, hl[i]);
  }
}

// ---------------------------------------------------------------------------
// Kernel: scan phase C — register-y (full unroll), yt aliased over dxi.
// ---------------------------------------------------------------------------
__global__ __launch_bounds__(256) void k_scanC(const float* __restrict__ dtT,
                                               const float* __restrict__ xcT,
                                               const float* __restrict__ bcT,
                                               const float* __restrict__ zT,
                                               const float* __restrict__ A_log,
                                               const float* __restrict__ Dp,
                                               const float* __restrict__ hinit,
                                               unsigned short* __restrict__ yH) {
  __shared__ float dxi[32 * 132];      // staging; aliased by yt[32*72] post-loop
  __shared__ float bc4[8 * 260];
  float* yt = dxi;
  const int b = blockIdx.z, ch = blockIdx.x, d0 = blockIdx.y * 32;
  const int l0 = ch * kCL, tid = threadIdx.x;
  {
    const int ds = tid >> 3, ng = tid & 7;
    const float4* dsrc = (const float4*)&dtT[((size_t)b * kE + d0 + ds) * kL + l0 + 8 * ng];
    const float4* xsrc = (const float4*)&xcT[((size_t)b * kE + d0 + ds) * kL + l0 + 8 * ng];
    float* wr = &dxi[ds * 132 + 16 * ng];
    #pragma unroll
    for (int m = 0; m < 2; ++m) {
      const float4 dv = dsrc[m], xv = xsrc[m];
      *(float4*)&wr[8 * m]     = make_float4(dv.x, dv.x * xv.x, dv.y, dv.y * xv.y);
      *(float4*)&wr[8 * m + 4] = make_float4(dv.z, dv.z * xv.z, dv.w, dv.w * xv.w);
    }
  }
  if (tid < 128) {
    const int ng = tid & 7, lq = tid >> 3;     // lq 0..15
    const float4 b0 = *(const float4*)&bcT[((size_t)b * 32 + 2 * ng) * kL + l0 + 4 * lq];
    const float4 c0 = *(const float4*)&bcT[((size_t)b * 32 + 16 + 2 * ng) * kL + l0 + 4 * lq];
    const float4 b1 = *(const float4*)&bcT[((size_t)b * 32 + 2 * ng + 1) * kL + l0 + 4 * lq];
    const float4 c1 = *(const float4*)&bcT[((size_t)b * 32 + 17 + 2 * ng) * kL + l0 + 4 * lq];
    float* wr = &bc4[ng * 260 + 16 * lq];
    *(float4*)&wr[0]  = make_float4(b0.x, c0.x, b1.x, c1.x);
    *(float4*)&wr[4]  = make_float4(b0.y, c0.y, b1.y, c1.y);
    *(float4*)&wr[8]  = make_float4(b0.z, c0.z, b1.z, c1.z);
    *(float4*)&wr[12] = make_float4(b0.w, c0.w, b1.w, c1.w);
  }
  __syncthreads();
  const int ds = tid >> 3, ng = tid & 7;
  const int d = d0 + ds;
  const float2 Al = *(const float2*)&A_log[d * kN + 2 * ng];
  const float Av0 = -__expf(Al.x), Av1 = -__expf(Al.y);
  const size_t hbase = (((size_t)b * kNC + ch) * kE + d) * kN + 2 * ng;
  const float2 hv = *(const float2*)&hinit[hbase];
  float h0 = hv.x, h1 = hv.y;
  const float* drow = &dxi[ds * 132];
  const float* brow = &bc4[ng * 260];
  float yreg[8];
  #pragma unroll
  for (int l = 0; l < kCL; l += 2) {
    const float4 du  = *(const float4*)&drow[2 * l];
    const float4 bcA = *(const float4*)&brow[4 * l];
    const float4 bcB = *(const float4*)&brow[4 * l + 4];
    h0 = fmaf(__expf(Av0 * du.x), h0, bcA.x * du.y);
    h1 = fmaf(__expf(Av1 * du.x), h1, bcA.z * du.y);
    const float ylo = dpp_red8(fmaf(h0, bcA.y, h1 * bcA.w));
    h0 = fmaf(__expf(Av0 * du.z), h0, bcB.x * du.w);
    h1 = fmaf(__expf(Av1 * du.z), h1, bcB.z * du.w);
    const float yhi = dpp_red8(fmaf(h0, bcB.y, h1 * bcB.w));
    if (ng == (l & 7))       yreg[l >> 3] = ylo;
    if (ng == ((l + 1) & 7)) yreg[l >> 3] = yhi;
  }
  __syncthreads();
  #pragma unroll
  for (int k = 0; k < 8; ++k)
    yt[ds * 72 + 8 * k + ng] = yreg[k];
  __syncthreads();
  const int l = tid >> 2, g = tid & 3;
  u16x8 ov;
  #pragma unroll
  for (int i = 0; i < 8; ++i) {
    const int dd = g * 8 + i;
    const float yv = yt[dd * 72 + l];
    const float xv = xcT[((size_t)b * kE + d0 + dd) * kL + l0 + l];
    const float zv = zT[((size_t)b * kE + d0 + dd) * kL + l0 + l];
    const float o = fmaf(xv, Dp[d0 + dd], yv) * silu(zv);
    ov[i] = f2bf(o);
  }
  *(u16x8*)&yH[((size_t)b * kL + l0 + l) * kE + d0 + g * 8] = ov;
}

// ---------------------------------------------------------------------------
extern "C" void kernel_launch(void* const* d_in, const int* in_sizes, int n_in,
                              void* d_out, int out_size, void* d_ws, size_t ws_size,
                              hipStream_t stream) {
  (void)in_sizes; (void)n_in; (void)out_size; (void)ws_size;
  const float* x      = (const float*)d_in[0];
  const float* ln_w   = (const float*)d_in[1];
  const float* ln_b   = (const float*)d_in[2];
  const float* W_in   = (const float*)d_in[3];
  const float* conv_w = (const float*)d_in[4];
  const float* conv_b = (const float*)d_in[5];
  const float* W_x    = (const float*)d_in[6];
  const float* W_dt   = (const float*)d_in[7];
  const float* b_dt   = (const float*)d_in[8];
  const float* A_log  = (const float*)d_in[9];
  const float* Dp     = (const float*)d_in[10];
  const float* W_out  = (const float*)d_in[11];
  float* out = (float*)d_out;
  float* ws  = (float*)d_ws;

  // workspace layout (float offsets), ~77.9 MB
  float* zT    = ws + 4194304;          // 4,194,304 fp32 [b][256][L]
  float* xcT   = ws + 8388608;          // 4,194,304
  float* dtT   = ws + 12582912;         // 4,194,304; alias: xnH bf16 (dead before dbc)
  float* bcT   = ws + 16777216;         //   524,288 [b][32][L]
  float* hloc  = ws + 17301504;         // 1,048,576 (aliases xcH; xcH dead after dbc)
  float* aprod = ws + 18350080;         // 1,048,576
  unsigned short* xnH  = (unsigned short*)(ws + 12582912);
  unsigned short* xcH  = (unsigned short*)(ws + 17301504);
  unsigned short* yH   = (unsigned short*)(ws);             // slot 0 (xiT eliminated)
  unsigned short* WinF = (unsigned short*)(ws + 19398656);  //  65,536 u16
  unsigned short* WcatF = WinF + 65536;                     //  73,728 u16
  unsigned short* WoutF = WinF + 139264;                    //  32,768 u16

  k_pre   <<<340, 256, 0, stream>>>(W_in, W_x, W_dt, W_out, WinF, WcatF, WoutF,
                                    x, ln_w, ln_b, xnH);
  k_g1conv<<<dim3(kL / 64, 4, kB), 256, 0, stream>>>(xnH, WinF, W_in, conv_w, conv_b,
                                                     zT, xcT, xcH);
  k_mfma<256, 288, 2, 1><<<dim3(kL / 64, 2, kB), 256, 0, stream>>>(xcH, WcatF, b_dt, dtT, bcT);
  k_scanA <<<dim3(kNC, kE / 32, kB), 256, 0, stream>>>(dtT, xcT, bcT, A_log, hloc, aprod);
  k_prefix8<<<256, 256, 0, stream>>>(hloc, aprod);
  k_scanC <<<dim3(kNC, kE / 32, kB), 256, 0, stream>>>(dtT, xcT, bcT, zT, A_log, Dp, hloc, yH);
  k_mfma<256, 128, 1, 2><<<dim3(kL / 64, 1, kB), 256, 0, stream>>>(yH, WoutF, nullptr, out, nullptr);
}